// Round 10
// baseline (4815.922 us; speedup 1.0000x reference)
//
#include <hip/hip_runtime.h>
#include <stdint.h>

#define B_ 256
#define T_ 512
#define DIN 512
#define H_ 1024
#define BT (B_*T_)
#define G3 (3*H_)
#define RS 100   // red row stride (floats)

typedef unsigned short u16;
typedef unsigned int u32;
typedef unsigned long long u64;
typedef __attribute__((ext_vector_type(8))) __bf16 bf16x8;
typedef __attribute__((ext_vector_type(4))) float f4;

__device__ __forceinline__ u16 f2bf(float f){
  u32 u = __float_as_uint(f);
  u32 r = u + 0x7fffu + ((u>>16)&1u);
  return (u16)(r>>16);
}
__device__ __forceinline__ float bf2f(u16 u){ return __uint_as_float(((u32)u)<<16); }
__device__ __forceinline__ float sigm(float x){ return 1.f/(1.f+__expf(-x)); }
__device__ __forceinline__ float tanh_f(float x){
  x = fminf(fmaxf(x, -15.f), 15.f);
  float e = __expf(2.f*x);
  return (e-1.f)/(e+1.f);
}
__device__ __forceinline__ void gload_lds16(const u16* g, u16* l){
  __builtin_amdgcn_global_load_lds((const __attribute__((address_space(1))) void*)g,
                                   (__attribute__((address_space(3))) void*)l, 16, 0, 0);
}
__device__ __forceinline__ f4 mfma16(bf16x8 a, bf16x8 b, f4 c){
  return __builtin_amdgcn_mfma_f32_16x16x32_bf16(a, b, c, 0, 0, 0);
}

// ---------------- cast f32 -> bf16, 8 elems/thread ----------------
__global__ __launch_bounds__(256) void k_cast(const float* __restrict__ s,
                                              u16* __restrict__ d, int n8){
  int i = blockIdx.x*256 + threadIdx.x;
  int st = gridDim.x*256;
  for (; i < n8; i += st){
    float4 a = ((const float4*)s)[i*2+0];
    float4 b = ((const float4*)s)[i*2+1];
    uint4 o;
    o.x = (u32)f2bf(a.x) | ((u32)f2bf(a.y)<<16);
    o.y = (u32)f2bf(a.z) | ((u32)f2bf(a.w)<<16);
    o.z = (u32)f2bf(b.x) | ((u32)f2bf(b.y)<<16);
    o.w = (u32)f2bf(b.z) | ((u32)f2bf(b.w)<<16);
    ((uint4*)d)[i] = o;
  }
}

// ---------------- prep: per-row active-step compression of mask ----------------
__global__ __launch_bounds__(256) void k_prep(const float* __restrict__ mask,
                                              u16* __restrict__ act, u16* __restrict__ idx,
                                              int* __restrict__ nact, int* __restrict__ meta){
  int b = blockIdx.x, tid = threadIdx.x;
  __shared__ int ps[256];
  const float* mr = mask + (size_t)b*T_;
  int a0 = (mr[2*tid]   > 0.5f) ? 1 : 0;
  int a1 = (mr[2*tid+1] > 0.5f) ? 1 : 0;
  ps[tid] = a0 + a1;
  __syncthreads();
  for (int off=1; off<256; off<<=1){
    int v = ps[tid];
    int u = (tid >= off) ? ps[tid-off] : 0;
    __syncthreads();
    ps[tid] = v + u;
    __syncthreads();
  }
  int excl = tid ? ps[tid-1] : 0;
  int i0 = excl + a0;
  int i1 = i0 + a1;
  idx[b*T_ + 2*tid]   = (u16)i0;
  idx[b*T_ + 2*tid+1] = (u16)i1;
  if (a0) act[b*T_ + i0-1] = (u16)(2*tid);
  if (a1) act[b*T_ + i1-1] = (u16)(2*tid+1);
  int na = ps[255];
  if (tid == 0){ nact[b] = na; atomicMax(&meta[0], na); }
  for (int s = na + tid; s < T_; s += 256) act[b*T_ + s] = (u16)(T_-1);
}

// ---------------- phase1c: x_c[s][b] = glu(inputs[b][act[b][s]]) -- M-compressed ----------------
// Row m' = s*256 + b. A-row gather via per-lane global_load_lds source address.
__global__ __launch_bounds__(256) void k_phase1c(
    const u16* __restrict__ A, const u16* __restrict__ Wi, const u16* __restrict__ Wg,
    const u16* __restrict__ act, const int* __restrict__ meta,
    const float* __restrict__ bin, const float* __restrict__ bgt,
    const float* __restrict__ cbi, const float* __restrict__ cbg,
    u16* __restrict__ X){
  __shared__ u16 As[128*32];
  __shared__ u16 Bi[64*32];
  __shared__ u16 Bg[64*32];
  int tid = threadIdx.x;
  int lane = tid & 63, wave = tid >> 6;
  int l15 = lane & 15, l4 = lane >> 4;
  int blk = blockIdx.x;
  int chunk = blk >> 7;
  int wi = blk & 127;
  int m0 = (chunk*8 + (wi & 7))*128;
  int n0 = (wi >> 3)*64;
  if (m0 >= (meta[0] << 8)) return;    // beyond 256*Smax: nothing to compute
  int mo = (wave&1)*64, no = (wave>>1)*32;

  // per-thread gathered A-row bases (constant across K): rows m0+(tid>>2), +64
  int r0 = m0 + (tid>>2), r1 = r0 + 64;
  int b0r = r0 & 255, s0r = r0 >> 8;
  int b1r = r1 & 255, s1r = r1 >> 8;
  const u16* a0p = A + ((size_t)b0r*T_ + act[b0r*T_ + s0r])*DIN + (tid&3)*8;
  const u16* a1p = A + ((size_t)b1r*T_ + act[b1r*T_ + s1r])*DIN + (tid&3)*8;

  f4 acc1[4][2] = {}; f4 acc2[4][2] = {};
  for (int k0 = 0; k0 < DIN; k0 += 32){
    gload_lds16(a0p + k0, As + wave*512);
    gload_lds16(a1p + k0, As + (4+wave)*512);
    int u = tid;
    gload_lds16(Wi + (n0 + (u>>2))*DIN + k0 + (u&3)*8, Bi + wave*512);
    gload_lds16(Wg + (n0 + (u>>2))*DIN + k0 + (u&3)*8, Bg + wave*512);
    __syncthreads();
    bf16x8 a[4], b1[2], b2[2];
    #pragma unroll
    for (int mt=0; mt<4; mt++) a[mt] = *(const bf16x8*)&As[(mo+mt*16+l15)*32 + l4*8];
    #pragma unroll
    for (int nt=0; nt<2; nt++){
      b1[nt] = *(const bf16x8*)&Bi[(no+nt*16+l15)*32 + l4*8];
      b2[nt] = *(const bf16x8*)&Bg[(no+nt*16+l15)*32 + l4*8];
    }
    #pragma unroll
    for (int mt=0; mt<4; mt++)
      #pragma unroll
      for (int nt=0; nt<2; nt++){
        acc1[mt][nt] = mfma16(a[mt], b1[nt], acc1[mt][nt]);
        acc2[mt][nt] = mfma16(a[mt], b2[nt], acc2[mt][nt]);
      }
    __syncthreads();
  }
  #pragma unroll
  for (int mt=0; mt<4; mt++)
   #pragma unroll
   for (int nt=0; nt<2; nt++)
    #pragma unroll
    for (int i=0; i<4; i++){
      int m = m0 + mo + mt*16 + l4*4 + i;
      int n = n0 + no + nt*16 + l15;
      int b = m & 255;                 // m' = s*256 + b
      float xl = acc1[mt][nt][i] + bin[n] + cbi[b*H_ + n];
      float gl = acc2[mt][nt][i] + bgt[n] + cbg[b*H_ + n];
      X[(size_t)m*H_ + n] = f2bf(tanh_f(xl) * sigm(gl));
    }
}

// ---------------- phase2c: gi_c[m'] = x_c[m'] @ W_ih^T + b_ih  (linear M-compressed) ----------------
__global__ __launch_bounds__(256) void k_phase2c(
    const u16* __restrict__ X, const u16* __restrict__ W,
    const int* __restrict__ meta, const float* __restrict__ bih,
    u16* __restrict__ GI){
  __shared__ u16 As[128*32];
  __shared__ u16 Bs[128*32];
  int tid = threadIdx.x;
  int lane = tid & 63, wave = tid >> 6;
  int l15 = lane & 15, l4 = lane >> 4;
  int blk = blockIdx.x;
  int chunk = blk / 96;
  int wi = blk % 96;
  int m0 = (chunk*4 + (wi & 3))*128;
  int n0 = (wi >> 2)*128;
  if (m0 >= (meta[0] << 8)) return;
  int mo = (wave&1)*64, no = (wave>>1)*64;
  f4 acc[4][4] = {};
  for (int k0 = 0; k0 < H_; k0 += 32){
    int u = tid;
    gload_lds16(X + (m0 + (u>>2))*H_ + k0 + (u&3)*8, As + wave*512);
    gload_lds16(W + (n0 + (u>>2))*H_ + k0 + (u&3)*8, Bs + wave*512);
    u = 256 + tid;
    gload_lds16(X + (m0 + (u>>2))*H_ + k0 + (u&3)*8, As + (4+wave)*512);
    gload_lds16(W + (n0 + (u>>2))*H_ + k0 + (u&3)*8, Bs + (4+wave)*512);
    __syncthreads();
    bf16x8 a[4], b[4];
    #pragma unroll
    for (int t2=0; t2<4; t2++){
      a[t2] = *(const bf16x8*)&As[(mo+t2*16+l15)*32 + l4*8];
      b[t2] = *(const bf16x8*)&Bs[(no+t2*16+l15)*32 + l4*8];
    }
    #pragma unroll
    for (int mt=0; mt<4; mt++)
      #pragma unroll
      for (int nt=0; nt<4; nt++)
        acc[mt][nt] = mfma16(a[mt], b[nt], acc[mt][nt]);
    __syncthreads();
  }
  #pragma unroll
  for (int mt=0; mt<4; mt++)
   #pragma unroll
   for (int nt=0; nt<4; nt++)
    #pragma unroll
    for (int i=0; i<4; i++){
      int m = m0 + mo + mt*16 + l4*4 + i;
      int n = n0 + no + nt*16 + l15;
      GI[(size_t)m*G3 + n] = f2bf(acc[mt][nt][i] + bih[n]);
    }
}

// ---------------- compressed scan: R7-proven structure, s-linear GI ----------------
// R8 lesson: flag detection must be ONE lane-parallel load (wave0 polls all 32 flags).
__global__ __launch_bounds__(256,1) void k_scan_c(
    const u16* __restrict__ GI, const u16* __restrict__ Whh,
    const float* __restrict__ bhh,
    const int* __restrict__ nact, const int* __restrict__ meta,
    u16* __restrict__ hcomp, int* __restrict__ flags){
  __shared__ u16 hs[32*1024];          // 64 KiB staged h (swizzled 16B granules)
  __shared__ float red[2*32*RS];       // 25.6 KiB partial sums
  int tid = threadIdx.x;
  int lane = tid & 63, wave = tid >> 6;
  int l15 = lane & 15, l4 = lane >> 4;
  int bi = blockIdx.x & 7, ji = blockIdx.x >> 3;
  int b0 = bi*32, j0 = ji*32;
  int kwi = wave & 1;
  int kw2 = kwi*512;
  int nw  = (wave>>1)*48;

  f4 wff[3][16];                       // resident W_hh slice, asm-pinned
  #pragma unroll
  for (int nt=0; nt<3; nt++){
    int c  = nw + nt*16 + l15;
    int wrow = (c>>5)*H_ + j0 + (c&31);
    #pragma unroll
    for (int ks=0; ks<16; ks++){
      wff[nt][ks] = *(const f4*)&Whh[(size_t)wrow*H_ + kw2 + ks*32 + l4*8];
      asm volatile("" : "+v"(wff[nt][ks]));
    }
  }

  int urow = tid >> 3;
  int c0 = (tid & 7)*4;
  int row_b = b0 + urow;
  float bh[3][4];
  #pragma unroll
  for (int g=0; g<3; g++)
    #pragma unroll
    for (int ci=0; ci<4; ci++)
      bh[g][ci] = bhh[g*H_ + j0 + c0 + ci];
  float hreg[4] = {0.f,0.f,0.f,0.f};
  int na = nact[row_b];
  int Smax = meta[0];

  for (int s=0; s<Smax; s++){
    // ---- GI gather, s-linear (in flight during poll) ----
    const u16* gib = GI + ((size_t)s*B_ + row_b)*G3 + j0 + c0;
    u64 gv0 = *(const u64*)(gib);
    u64 gv1 = *(const u64*)(gib + H_);
    u64 gv2 = *(const u64*)(gib + 2*H_);

    // ---- wait: wave 0 polls 32 padded flags in ONE lane-parallel load ----
    if (wave == 0 && s > 0){
      const int* fp = flags + (bi*32 + (lane & 31))*4;
      u32 it = 0;
      for (;;){
        int f = __hip_atomic_load(fp, __ATOMIC_RELAXED, __HIP_MEMORY_SCOPE_AGENT);
        if (__all(f >= s)) break;
        __builtin_amdgcn_s_sleep(1);
        if (++it > 300000u) break;
      }
    }
    __syncthreads();

    // ---- stage h(s-1): 16 x dwordx4 sc0 sc1 plain loads -> swizzled LDS (b128) ----
    if (s == 0){
      uint4 z = {0,0,0,0};
      uint4* hs4 = (uint4*)hs;
      #pragma unroll
      for (int i=0; i<16; i++) hs4[i*256 + tid] = z;
    } else {
      const uint4* hb4 = (const uint4*)(hcomp + (size_t)(s-1)*(B_*H_) + (size_t)b0*H_);
      uint4 r[16];
      #pragma unroll
      for (int i=0; i<16; i++){
        const uint4* p = hb4 + i*256 + tid;
        asm volatile("global_load_dwordx4 %0, %1, off sc0 sc1" : "=v"(r[i]) : "v"(p));
      }
      asm volatile("s_waitcnt vmcnt(0)" ::: "memory");
      __builtin_amdgcn_sched_barrier(0);
      uint4* hs4 = (uint4*)hs;
      #pragma unroll
      for (int i=0; i<16; i++){
        int g = i*256 + tid;            // granule id over 32 rows x 128
        int row = g >> 7, col = g & 127;
        hs4[row*128 + (col ^ (row&7))] = r[i];
      }
    }
    __syncthreads();

    // ---- MFMA: gh partial (32 rows x 48 cols x K=512 per wave) ----
    f4 acc[2][3] = {};
    #pragma unroll
    for (int ks=0; ks<16; ks++){
      bf16x8 a[2];
      #pragma unroll
      for (int mt=0; mt<2; mt++){
        int row = mt*16 + l15;
        int c16 = (kw2>>3) + ks*4 + l4;
        a[mt] = *(const bf16x8*)&hs[row*1024 + ((c16 ^ (row&7))<<3)];
      }
      #pragma unroll
      for (int mt=0; mt<2; mt++)
        #pragma unroll
        for (int nt=0; nt<3; nt++)
          acc[mt][nt] = mfma16(a[mt], __builtin_bit_cast(bf16x8, wff[nt][ks]), acc[mt][nt]);
    }

    // ---- write partials to LDS ----
    #pragma unroll
    for (int mt=0; mt<2; mt++)
      #pragma unroll
      for (int nt=0; nt<3; nt++)
        #pragma unroll
        for (int i=0; i<4; i++)
          red[(kwi*32 + mt*16 + l4*4 + i)*RS + nw + nt*16 + l15] = acc[mt][nt][i];
    __syncthreads();

    // ---- elementwise GRU update (1 row x 4 cols per thread) ----
    {
      f4 gh[3];
      #pragma unroll
      for (int g=0; g<3; g++){
        f4 s0 = *(const f4*)&red[(0*32+urow)*RS + g*32 + c0];
        f4 s1 = *(const f4*)&red[(1*32+urow)*RS + g*32 + c0];
        gh[g] = s0 + s1;
      }
      bool active = (s < na);
      u16 hb16[4];
      #pragma unroll
      for (int ci=0; ci<4; ci++){
        float ir  = bf2f((u16)(gv0 >> (16*ci)));
        float iz  = bf2f((u16)(gv1 >> (16*ci)));
        float in_ = bf2f((u16)(gv2 >> (16*ci)));
        float r = sigm(ir + gh[0][ci] + bh[0][ci]);
        float z = sigm(iz + gh[1][ci] + bh[1][ci]);
        float n = tanh_f(in_ + r*(gh[2][ci] + bh[2][ci]));
        float hn = (1.f - z)*n + z*hreg[ci];
        hreg[ci] = active ? hn : hreg[ci];
        hb16[ci] = f2bf(hreg[ci]);
      }
      u64 pk = (u64)hb16[0] | ((u64)hb16[1]<<16) | ((u64)hb16[2]<<32) | ((u64)hb16[3]<<48);
      __hip_atomic_store((u64*)&hcomp[(size_t)s*(B_*H_) + (size_t)row_b*H_ + j0 + c0],
                         pk, __ATOMIC_RELAXED, __HIP_MEMORY_SCOPE_AGENT);
    }
    __syncthreads();                   // all threads' h stores drained before flag
    if (tid == 0)
      __hip_atomic_store(&flags[(bi*32 + ji)*4], s+1,
                         __ATOMIC_RELEASE, __HIP_MEMORY_SCOPE_AGENT);
  }
}

// ---------------- LayerNorm with hcomp gather: 8 rows (same b) per block ----------------
__global__ __launch_bounds__(256) void k_lng8(const u16* __restrict__ hcomp,
                                              const u16* __restrict__ idx,
                                              const float* __restrict__ g,
                                              const float* __restrict__ b,
                                              float* __restrict__ Y){
  int blk = blockIdx.x;
  int bb = blk >> 6, tt0 = (blk & 63)*8;
  int tid = threadIdx.x;
  float4 gg = ((const float4*)g)[tid];
  float4 bb4 = ((const float4*)b)[tid];
  __shared__ float ss[4], qq[4];
  int wave = tid >> 6;
  #pragma unroll
  for (int rr=0; rr<8; rr++){
    int tt = tt0 + rr;
    int s = (int)idx[bb*T_ + tt];
    float4 v;
    if (s == 0){
      v.x = v.y = v.z = v.w = 0.f;
    } else {
      u64 hv = *(const u64*)(hcomp + (size_t)(s-1)*(B_*H_) + (size_t)bb*H_ + tid*4);
      v.x = bf2f((u16)hv);
      v.y = bf2f((u16)(hv>>16));
      v.z = bf2f((u16)(hv>>32));
      v.w = bf2f((u16)(hv>>48));
    }
    float sm = v.x+v.y+v.z+v.w;
    float q = v.x*v.x+v.y*v.y+v.z*v.z+v.w*v.w;
    #pragma unroll
    for (int off=32; off; off>>=1){ sm += __shfl_down(sm, off); q += __shfl_down(q, off); }
    if ((tid&63)==0){ ss[wave]=sm; qq[wave]=q; }
    __syncthreads();
    sm = ss[0]+ss[1]+ss[2]+ss[3];
    q  = qq[0]+qq[1]+qq[2]+qq[3];
    float mu = sm*(1.f/H_);
    float var = q*(1.f/H_) - mu*mu;
    float rs = rsqrtf(var + 1e-5f);
    float4 o;
    o.x = (v.x-mu)*rs*gg.x + bb4.x;
    o.y = (v.y-mu)*rs*gg.y + bb4.y;
    o.z = (v.z-mu)*rs*gg.z + bb4.z;
    o.w = (v.w-mu)*rs*gg.w + bb4.w;
    ((float4*)(Y + ((size_t)bb*T_ + tt)*H_))[tid] = o;
    __syncthreads();
  }
}

// ================= fallback path (small ws): R9-proven uncompressed =================
__global__ __launch_bounds__(256) void k_phase1(
    const u16* __restrict__ A, const u16* __restrict__ Wi, const u16* __restrict__ Wg,
    const float* __restrict__ bin, const float* __restrict__ bgt,
    const float* __restrict__ cbi, const float* __restrict__ cbg,
    u16* __restrict__ X){
  __shared__ u16 As[128*32];
  __shared__ u16 Bi[64*32];
  __shared__ u16 Bg[64*32];
  int tid = threadIdx.x;
  int lane = tid & 63, wave = tid >> 6;
  int l15 = lane & 15, l4 = lane >> 4;
  int blk = blockIdx.x;
  int chunk = blk >> 7;
  int wi = blk & 127;
  int m0 = (chunk*8 + (wi & 7))*128;
  int n0 = (wi >> 3)*64;
  int mo = (wave&1)*64, no = (wave>>1)*32;
  f4 acc1[4][2] = {}; f4 acc2[4][2] = {};
  for (int k0 = 0; k0 < DIN; k0 += 32){
    int u = tid;
    gload_lds16(A + (m0 + (u>>2))*DIN + k0 + (u&3)*8, As + wave*512);
    u = 256 + tid;
    gload_lds16(A + (m0 + (u>>2))*DIN + k0 + (u&3)*8, As + (4+wave)*512);
    u = tid;
    gload_lds16(Wi + (n0 + (u>>2))*DIN + k0 + (u&3)*8, Bi + wave*512);
    gload_lds16(Wg + (n0 + (u>>2))*DIN + k0 + (u&3)*8, Bg + wave*512);
    __syncthreads();
    bf16x8 a[4], b1[2], b2[2];
    #pragma unroll
    for (int mt=0; mt<4; mt++) a[mt] = *(const bf16x8*)&As[(mo+mt*16+l15)*32 + l4*8];
    #pragma unroll
    for (int nt=0; nt<2; nt++){
      b1[nt] = *(const bf16x8*)&Bi[(no+nt*16+l15)*32 + l4*8];
      b2[nt] = *(const bf16x8*)&Bg[(no+nt*16+l15)*32 + l4*8];
    }
    #pragma unroll
    for (int mt=0; mt<4; mt++)
      #pragma unroll
      for (int nt=0; nt<2; nt++){
        acc1[mt][nt] = mfma16(a[mt], b1[nt], acc1[mt][nt]);
        acc2[mt][nt] = mfma16(a[mt], b2[nt], acc2[mt][nt]);
      }
    __syncthreads();
  }
  #pragma unroll
  for (int mt=0; mt<4; mt++)
   #pragma unroll
   for (int nt=0; nt<2; nt++)
    #pragma unroll
    for (int i=0; i<4; i++){
      int m = m0 + mo + mt*16 + l4*4 + i;
      int n = n0 + no + nt*16 + l15;
      int b = m >> 9;
      float xl = acc1[mt][nt][i] + bin[n] + cbi[b*H_ + n];
      float gl = acc2[mt][nt][i] + bgt[n] + cbg[b*H_ + n];
      X[(size_t)m*H_ + n] = f2bf(tanh_f(xl) * sigm(gl));
    }
}

__global__ __launch_bounds__(256) void k_phase2(
    const u16* __restrict__ X, const u16* __restrict__ W,
    const float* __restrict__ bih, u16* __restrict__ GI){
  __shared__ u16 As[128*32];
  __shared__ u16 Bs[128*32];
  int tid = threadIdx.x;
  int lane = tid & 63, wave = tid >> 6;
  int l15 = lane & 15, l4 = lane >> 4;
  int blk = blockIdx.x;
  int chunk = blk / 96;
  int wi = blk % 96;
  int m0 = (chunk*4 + (wi & 3))*128;
  int n0 = (wi >> 2)*128;
  int mo = (wave&1)*64, no = (wave>>1)*64;
  f4 acc[4][4] = {};
  for (int k0 = 0; k0 < H_; k0 += 32){
    int u = tid;
    gload_lds16(X + (m0 + (u>>2))*H_ + k0 + (u&3)*8, As + wave*512);
    gload_lds16(W + (n0 + (u>>2))*H_ + k0 + (u&3)*8, Bs + wave*512);
    u = 256 + tid;
    gload_lds16(X + (m0 + (u>>2))*H_ + k0 + (u&3)*8, As + (4+wave)*512);
    gload_lds16(W + (n0 + (u>>2))*H_ + k0 + (u&3)*8, Bs + (4+wave)*512);
    __syncthreads();
    bf16x8 a[4], b[4];
    #pragma unroll
    for (int t2=0; t2<4; t2++){
      a[t2] = *(const bf16x8*)&As[(mo+t2*16+l15)*32 + l4*8];
      b[t2] = *(const bf16x8*)&Bs[(no+t2*16+l15)*32 + l4*8];
    }
    #pragma unroll
    for (int mt=0; mt<4; mt++)
      #pragma unroll
      for (int nt=0; nt<4; nt++)
        acc[mt][nt] = mfma16(a[mt], b[nt], acc[mt][nt]);
    __syncthreads();
  }
  #pragma unroll
  for (int mt=0; mt<4; mt++)
   #pragma unroll
   for (int nt=0; nt<4; nt++)
    #pragma unroll
    for (int i=0; i<4; i++){
      int m = m0 + mo + mt*16 + l4*4 + i;
      int n = n0 + no + nt*16 + l15;
      int b = m >> 9, t = m & 511;
      GI[((size_t)t*B_ + b)*G3 + n] = f2bf(acc[mt][nt][i] + bih[n]);
    }
}

__global__ __launch_bounds__(256,1) void k_scan_d(
    const u16* __restrict__ GI, const u16* __restrict__ Whh,
    const float* __restrict__ bhh, const float* __restrict__ mask,
    u16* __restrict__ hbuf, int* __restrict__ flags, float* __restrict__ Y){
  __shared__ u16 hs[32*1024];
  __shared__ float red[2*32*RS];
  int tid = threadIdx.x;
  int lane = tid & 63, wave = tid >> 6;
  int l15 = lane & 15, l4 = lane >> 4;
  int bi = blockIdx.x & 7, ji = blockIdx.x >> 3;
  int b0 = bi*32, j0 = ji*32;
  int kwi = wave & 1;
  int kw2 = kwi*512;
  int nw  = (wave>>1)*48;
  f4 wff[3][16];
  #pragma unroll
  for (int nt=0; nt<3; nt++){
    int c  = nw + nt*16 + l15;
    int wrow = (c>>5)*H_ + j0 + (c&31);
    #pragma unroll
    for (int ks=0; ks<16; ks++){
      wff[nt][ks] = *(const f4*)&Whh[(size_t)wrow*H_ + kw2 + ks*32 + l4*8];
      asm volatile("" : "+v"(wff[nt][ks]));
    }
  }
  int urow = tid >> 3;
  int c0 = (tid & 7)*4;
  float bh[3][4];
  #pragma unroll
  for (int g=0; g<3; g++)
    #pragma unroll
    for (int ci=0; ci<4; ci++)
      bh[g][ci] = bhh[g*H_ + j0 + c0 + ci];
  float hreg[4] = {0.f,0.f,0.f,0.f};
  const float* mrow = mask + (size_t)(b0+urow)*T_;
  u64* hs64 = (u64*)hs;
  for (int t=0; t<T_; t++){
    const u16* gib = GI + ((size_t)t*B_ + (b0+urow))*G3 + j0 + c0;
    u64 gv0 = *(const u64*)(gib);
    u64 gv1 = *(const u64*)(gib + H_);
    u64 gv2 = *(const u64*)(gib + 2*H_);
    float msk = mrow[t];
    if (wave == 0 && t > 0){
      const int* fp = flags + (bi*32 + (lane & 31))*4;
      u32 it = 0;
      for (;;){
        int f = __hip_atomic_load(fp, __ATOMIC_RELAXED, __HIP_MEMORY_SCOPE_AGENT);
        if (__all(f >= t)) break;
        __builtin_amdgcn_s_sleep(1);
        if (++it > 300000u) break;
      }
    }
    __syncthreads();
    {
      const u64* hb = (const u64*)hbuf + (size_t)(t&1)*(B_*H_/4) + (size_t)b0*256;
      #pragma unroll
      for (int ib=0; ib<4; ib++){
        u64 v[8];
        #pragma unroll
        for (int i=0; i<8; i++)
          v[i] = __hip_atomic_load(hb + (ib*8+i)*256 + tid,
                                   __ATOMIC_RELAXED, __HIP_MEMORY_SCOPE_AGENT);
        #pragma unroll
        for (int i=0; i<8; i++){
          int row = ib*8 + i;
          int phys = (((tid>>1) ^ (row&7))<<1) | (tid&1);
          hs64[row*256 + phys] = v[i];
        }
      }
    }
    __syncthreads();
    f4 acc[2][3] = {};
    #pragma unroll
    for (int ks=0; ks<16; ks++){
      bf16x8 a[2];
      #pragma unroll
      for (int mt=0; mt<2; mt++){
        int row = mt*16 + l15;
        int c16 = (kw2>>3) + ks*4 + l4;
        a[mt] = *(const bf16x8*)&hs[row*1024 + ((c16 ^ (row&7))<<3)];
      }
      #pragma unroll
      for (int mt=0; mt<2; mt++)
        #pragma unroll
        for (int nt=0; nt<3; nt++)
          acc[mt][nt] = mfma16(a[mt], __builtin_bit_cast(bf16x8, wff[nt][ks]), acc[mt][nt]);
    }
    #pragma unroll
    for (int mt=0; mt<2; mt++)
      #pragma unroll
      for (int nt=0; nt<3; nt++)
        #pragma unroll
        for (int i=0; i<4; i++)
          red[(kwi*32 + mt*16 + l4*4 + i)*RS + nw + nt*16 + l15] = acc[mt][nt][i];
    __syncthreads();
    {
      f4 gh[3];
      #pragma unroll
      for (int g=0; g<3; g++){
        f4 s0 = *(const f4*)&red[(0*32+urow)*RS + g*32 + c0];
        f4 s1 = *(const f4*)&red[(1*32+urow)*RS + g*32 + c0];
        gh[g] = s0 + s1;
      }
      u16 hb16[4];
      float yv[4];
      #pragma unroll
      for (int ci=0; ci<4; ci++){
        float ir  = bf2f((u16)(gv0 >> (16*ci)));
        float iz  = bf2f((u16)(gv1 >> (16*ci)));
        float in_ = bf2f((u16)(gv2 >> (16*ci)));
        float r = sigm(ir + gh[0][ci] + bh[0][ci]);
        float z = sigm(iz + gh[1][ci] + bh[1][ci]);
        float n = tanh_f(in_ + r*(gh[2][ci] + bh[2][ci]));
        float hn = (1.f - z)*n + z*hreg[ci];
        hreg[ci] = (msk > 0.5f) ? hn : hreg[ci];
        hb16[ci] = f2bf(hreg[ci]);
        yv[ci] = hreg[ci];
      }
      u64 pk = (u64)hb16[0] | ((u64)hb16[1]<<16) | ((u64)hb16[2]<<32) | ((u64)hb16[3]<<48);
      __hip_atomic_store((u64*)&hbuf[(size_t)((t+1)&1)*(B_*H_) + (size_t)(b0+urow)*H_ + j0 + c0],
                         pk, __ATOMIC_RELAXED, __HIP_MEMORY_SCOPE_AGENT);
      float4 yq; yq.x=yv[0]; yq.y=yv[1]; yq.z=yv[2]; yq.w=yv[3];
      *(float4*)&Y[((size_t)(b0+urow)*T_ + t)*H_ + j0 + c0] = yq;
    }
    __syncthreads();
    if (tid == 0)
      __hip_atomic_store(&flags[(bi*32 + ji)*4], t+1,
                         __ATOMIC_RELEASE, __HIP_MEMORY_SCOPE_AGENT);
  }
}

__global__ __launch_bounds__(256) void k_ln(float* __restrict__ Y,
                                            const float* __restrict__ g,
                                            const float* __restrict__ b){
  int row = blockIdx.x, tid = threadIdx.x;
  float4 v = ((const float4*)(Y + (size_t)row*H_))[tid];
  float s = v.x+v.y+v.z+v.w;
  float q = v.x*v.x+v.y*v.y+v.z*v.z+v.w*v.w;
  #pragma unroll
  for (int off=32; off; off>>=1){ s += __shfl_down(s, off); q += __shfl_down(q, off); }
  __shared__ float ss[4], qq[4];
  int wave = tid >> 6;
  if ((tid&63)==0){ ss[wave]=s; qq[wave]=q; }
  __syncthreads();
  s = ss[0]+ss[1]+ss[2]+ss[3];
  q = qq[0]+qq[1]+qq[2]+qq[3];
  float mu = s*(1.f/H_);
  float var = q*(1.f/H_) - mu*mu;
  float rs = rsqrtf(var + 1e-5f);
  float4 gg = ((const float4*)g)[tid];
  float4 bb = ((const float4*)b)[tid];
  float4 o;
  o.x = (v.x-mu)*rs*gg.x + bb.x;
  o.y = (v.y-mu)*rs*gg.y + bb.y;
  o.z = (v.z-mu)*rs*gg.z + bb.z;
  o.w = (v.w-mu)*rs*gg.w + bb.w;
  ((float4*)(Y + (size_t)row*H_))[tid] = o;
}

extern "C" void kernel_launch(void* const* d_in, const int* in_sizes, int n_in,
                              void* d_out, int out_size, void* d_ws, size_t ws_size,
                              hipStream_t stream){
  const float* inputs = (const float*)d_in[0];
  const float* mask   = (const float*)d_in[1];
  const float* cbi    = (const float*)d_in[2];
  const float* cbg    = (const float*)d_in[3];
  const float* W_in   = (const float*)d_in[4];
  const float* b_in   = (const float*)d_in[5];
  const float* W_gate = (const float*)d_in[6];
  const float* b_gate = (const float*)d_in[7];
  const float* W_ih   = (const float*)d_in[8];
  const float* b_ih   = (const float*)d_in[9];
  const float* W_hh   = (const float*)d_in[10];
  const float* b_hh   = (const float*)d_in[11];
  const float* ln_g   = (const float*)d_in[12];
  const float* ln_b   = (const float*)d_in[13];

  char* ws = (char*)d_ws;
  size_t o = 0;
  u16* in_bf  = (u16*)(ws + o); o += (size_t)BT*DIN*2;      // 128 MiB
  u16* wi_bf  = (u16*)(ws + o); o += (size_t)H_*DIN*2;
  u16* wg_bf  = (u16*)(ws + o); o += (size_t)H_*DIN*2;
  u16* wih_bf = (u16*)(ws + o); o += (size_t)G3*H_*2;
  u16* whh_bf = (u16*)(ws + o); o += (size_t)G3*H_*2;
  u16* gi_bf  = (u16*)(ws + o); o += (size_t)T_*B_*G3*2;    // 768 MiB
  u16* actb   = (u16*)(ws + o); o += (size_t)B_*T_*2;       // 256 KiB
  u16* idxb   = (u16*)(ws + o); o += (size_t)B_*T_*2;       // 256 KiB
  int* nactb  = (int*)(ws + o); o += (size_t)B_*4;
  int* meta   = (int*)(ws + o); o += 256;
  int* flags  = (int*)(ws + o); o += (size_t)8*32*4*4;
  u16* hbuf   = (u16*)(ws + o); o += (size_t)2*B_*H_*2;     // 1 MiB (fallback)
  size_t need_direct = o;
  u16* hcomp  = (u16*)(ws + o); o += (size_t)T_*B_*H_*2;    // 256 MiB (compressed)
  size_t need_comp = o;
  if (ws_size < need_direct) return;
  bool comp = (ws_size >= need_comp);

  hipMemsetAsync(flags, 0, (size_t)8*32*4*4, stream);
  if (comp) hipMemsetAsync(meta, 0, 256, stream);
  else      hipMemsetAsync(hbuf, 0, (size_t)2*B_*H_*2, stream);

  k_cast<<<2048,256,0,stream>>>(inputs, in_bf, BT*DIN/8);
  k_cast<<<256, 256,0,stream>>>(W_in,   wi_bf,  H_*DIN/8);
  k_cast<<<256, 256,0,stream>>>(W_gate, wg_bf,  H_*DIN/8);
  k_cast<<<1024,256,0,stream>>>(W_ih,   wih_bf, G3*H_/8);
  k_cast<<<1024,256,0,stream>>>(W_hh,   whh_bf, G3*H_/8);

  u16* X = (u16*)d_out;  // bf16 x_c staged in d_out; dead after phase2

  if (comp){
    k_prep<<<B_,256,0,stream>>>(mask, actb, idxb, nactb, meta);
    k_phase1c<<<16384,256,0,stream>>>(in_bf, wi_bf, wg_bf, actb, meta,
                                      b_in, b_gate, cbi, cbg, X);
    k_phase2c<<<24576,256,0,stream>>>(X, wih_bf, meta, b_ih, gi_bf);
    k_scan_c<<<256,256,0,stream>>>(gi_bf, whh_bf, b_hh, nactb, meta, hcomp, flags);
    k_lng8<<<BT/8,256,0,stream>>>(hcomp, idxb, ln_g, ln_b, (float*)d_out);
  } else {
    k_phase1<<<16384,256,0,stream>>>(in_bf, wi_bf, wg_bf, b_in, b_gate, cbi, cbg, X);
    k_phase2<<<24576,256,0,stream>>>(X, wih_bf, b_ih, gi_bf);
    k_scan_d<<<256,256,0,stream>>>(gi_bf, whh_bf, b_hh, mask, hbuf, flags, (float*)d_out);
    k_ln<<<BT,256,0,stream>>>((float*)d_out, ln_g, ln_b);
  }
}

// Round 11
// 3211.162 us; speedup vs baseline: 1.4997x; 1.4997x over previous
//
#include <hip/hip_runtime.h>
#include <stdint.h>

#define B_ 256
#define T_ 512
#define DIN 512
#define H_ 1024
#define BT (B_*T_)
#define G3 (3*H_)
#define RS 100   // red row stride (floats)

typedef unsigned short u16;
typedef unsigned int u32;
typedef unsigned long long u64;
typedef __attribute__((ext_vector_type(8))) __bf16 bf16x8;
typedef __attribute__((ext_vector_type(4))) float f4;

__device__ __forceinline__ u16 f2bf(float f){
  u32 u = __float_as_uint(f);
  u32 r = u + 0x7fffu + ((u>>16)&1u);
  return (u16)(r>>16);
}
__device__ __forceinline__ float bf2f(u16 u){ return __uint_as_float(((u32)u)<<16); }
__device__ __forceinline__ float sigm(float x){ return 1.f/(1.f+__expf(-x)); }
__device__ __forceinline__ float tanh_f(float x){
  x = fminf(fmaxf(x, -15.f), 15.f);
  float e = __expf(2.f*x);
  return (e-1.f)/(e+1.f);
}
__device__ __forceinline__ void gload_lds16(const u16* g, u16* l){
  __builtin_amdgcn_global_load_lds((const __attribute__((address_space(1))) void*)g,
                                   (__attribute__((address_space(3))) void*)l, 16, 0, 0);
}
__device__ __forceinline__ f4 mfma16(bf16x8 a, bf16x8 b, f4 c){
  return __builtin_amdgcn_mfma_f32_16x16x32_bf16(a, b, c, 0, 0, 0);
}

// ---------------- cast f32 -> bf16, 8 elems/thread ----------------
__global__ __launch_bounds__(256) void k_cast(const float* __restrict__ s,
                                              u16* __restrict__ d, int n8){
  int i = blockIdx.x*256 + threadIdx.x;
  int st = gridDim.x*256;
  for (; i < n8; i += st){
    float4 a = ((const float4*)s)[i*2+0];
    float4 b = ((const float4*)s)[i*2+1];
    uint4 o;
    o.x = (u32)f2bf(a.x) | ((u32)f2bf(a.y)<<16);
    o.y = (u32)f2bf(a.z) | ((u32)f2bf(a.w)<<16);
    o.z = (u32)f2bf(b.x) | ((u32)f2bf(b.y)<<16);
    o.w = (u32)f2bf(b.z) | ((u32)f2bf(b.w)<<16);
    ((uint4*)d)[i] = o;
  }
}

// ---------------- prep: per-row active-step compression of mask ----------------
__global__ __launch_bounds__(256) void k_prep(const float* __restrict__ mask,
                                              u16* __restrict__ act, u16* __restrict__ idx,
                                              int* __restrict__ nact, int* __restrict__ meta){
  int b = blockIdx.x, tid = threadIdx.x;
  __shared__ int ps[256];
  const float* mr = mask + (size_t)b*T_;
  int a0 = (mr[2*tid]   > 0.5f) ? 1 : 0;
  int a1 = (mr[2*tid+1] > 0.5f) ? 1 : 0;
  ps[tid] = a0 + a1;
  __syncthreads();
  for (int off=1; off<256; off<<=1){
    int v = ps[tid];
    int u = (tid >= off) ? ps[tid-off] : 0;
    __syncthreads();
    ps[tid] = v + u;
    __syncthreads();
  }
  int excl = tid ? ps[tid-1] : 0;
  int i0 = excl + a0;
  int i1 = i0 + a1;
  idx[b*T_ + 2*tid]   = (u16)i0;
  idx[b*T_ + 2*tid+1] = (u16)i1;
  if (a0) act[b*T_ + i0-1] = (u16)(2*tid);
  if (a1) act[b*T_ + i1-1] = (u16)(2*tid+1);
  int na = ps[255];
  if (tid == 0){ nact[b] = na; atomicMax(&meta[0], na); }
  for (int s = na + tid; s < T_; s += 256) act[b*T_ + s] = (u16)(T_-1);
}

// ---------------- phase1c: x_c[s][b] = glu(inputs[b][act[b][s]]) -- M-compressed ----------------
__global__ __launch_bounds__(256) void k_phase1c(
    const u16* __restrict__ A, const u16* __restrict__ Wi, const u16* __restrict__ Wg,
    const u16* __restrict__ act, const int* __restrict__ meta,
    const float* __restrict__ bin, const float* __restrict__ bgt,
    const float* __restrict__ cbi, const float* __restrict__ cbg,
    u16* __restrict__ X){
  __shared__ u16 As[128*32];
  __shared__ u16 Bi[64*32];
  __shared__ u16 Bg[64*32];
  int tid = threadIdx.x;
  int lane = tid & 63, wave = tid >> 6;
  int l15 = lane & 15, l4 = lane >> 4;
  int blk = blockIdx.x;
  int chunk = blk >> 7;
  int wi = blk & 127;
  int m0 = (chunk*8 + (wi & 7))*128;
  int n0 = (wi >> 3)*64;
  if (m0 >= (meta[0] << 8)) return;    // beyond 256*Smax: nothing to compute
  int mo = (wave&1)*64, no = (wave>>1)*32;

  int r0 = m0 + (tid>>2), r1 = r0 + 64;
  int b0r = r0 & 255, s0r = r0 >> 8;
  int b1r = r1 & 255, s1r = r1 >> 8;
  const u16* a0p = A + ((size_t)b0r*T_ + act[b0r*T_ + s0r])*DIN + (tid&3)*8;
  const u16* a1p = A + ((size_t)b1r*T_ + act[b1r*T_ + s1r])*DIN + (tid&3)*8;

  f4 acc1[4][2] = {}; f4 acc2[4][2] = {};
  for (int k0 = 0; k0 < DIN; k0 += 32){
    gload_lds16(a0p + k0, As + wave*512);
    gload_lds16(a1p + k0, As + (4+wave)*512);
    int u = tid;
    gload_lds16(Wi + (n0 + (u>>2))*DIN + k0 + (u&3)*8, Bi + wave*512);
    gload_lds16(Wg + (n0 + (u>>2))*DIN + k0 + (u&3)*8, Bg + wave*512);
    __syncthreads();
    bf16x8 a[4], b1[2], b2[2];
    #pragma unroll
    for (int mt=0; mt<4; mt++) a[mt] = *(const bf16x8*)&As[(mo+mt*16+l15)*32 + l4*8];
    #pragma unroll
    for (int nt=0; nt<2; nt++){
      b1[nt] = *(const bf16x8*)&Bi[(no+nt*16+l15)*32 + l4*8];
      b2[nt] = *(const bf16x8*)&Bg[(no+nt*16+l15)*32 + l4*8];
    }
    #pragma unroll
    for (int mt=0; mt<4; mt++)
      #pragma unroll
      for (int nt=0; nt<2; nt++){
        acc1[mt][nt] = mfma16(a[mt], b1[nt], acc1[mt][nt]);
        acc2[mt][nt] = mfma16(a[mt], b2[nt], acc2[mt][nt]);
      }
    __syncthreads();
  }
  #pragma unroll
  for (int mt=0; mt<4; mt++)
   #pragma unroll
   for (int nt=0; nt<2; nt++)
    #pragma unroll
    for (int i=0; i<4; i++){
      int m = m0 + mo + mt*16 + l4*4 + i;
      int n = n0 + no + nt*16 + l15;
      int b = m & 255;                 // m' = s*256 + b
      float xl = acc1[mt][nt][i] + bin[n] + cbi[b*H_ + n];
      float gl = acc2[mt][nt][i] + bgt[n] + cbg[b*H_ + n];
      X[(size_t)m*H_ + n] = f2bf(tanh_f(xl) * sigm(gl));
    }
}

// ---------------- phase2c: gi_c[m'] = x_c[m'] @ W_ih^T + b_ih (REVERSED chunk order) ----------------
// Reversed so the LAST-written GI region is s~0 = the scan's FIRST reads (L3-warm head).
__global__ __launch_bounds__(256) void k_phase2c(
    const u16* __restrict__ X, const u16* __restrict__ W,
    const int* __restrict__ meta, const float* __restrict__ bih,
    u16* __restrict__ GI){
  __shared__ u16 As[128*32];
  __shared__ u16 Bs[128*32];
  int tid = threadIdx.x;
  int lane = tid & 63, wave = tid >> 6;
  int l15 = lane & 15, l4 = lane >> 4;
  int blk = blockIdx.x;
  int chunk = 255 - (blk / 96);        // REVERSED: high m' first, s~0 written last
  int wi = blk % 96;
  int m0 = (chunk*4 + (wi & 3))*128;
  int n0 = (wi >> 2)*128;
  if (m0 >= (meta[0] << 8)) return;
  int mo = (wave&1)*64, no = (wave>>1)*64;
  f4 acc[4][4] = {};
  for (int k0 = 0; k0 < H_; k0 += 32){
    int u = tid;
    gload_lds16(X + (m0 + (u>>2))*H_ + k0 + (u&3)*8, As + wave*512);
    gload_lds16(W + (n0 + (u>>2))*H_ + k0 + (u&3)*8, Bs + wave*512);
    u = 256 + tid;
    gload_lds16(X + (m0 + (u>>2))*H_ + k0 + (u&3)*8, As + (4+wave)*512);
    gload_lds16(W + (n0 + (u>>2))*H_ + k0 + (u&3)*8, Bs + (4+wave)*512);
    __syncthreads();
    bf16x8 a[4], b[4];
    #pragma unroll
    for (int t2=0; t2<4; t2++){
      a[t2] = *(const bf16x8*)&As[(mo+t2*16+l15)*32 + l4*8];
      b[t2] = *(const bf16x8*)&Bs[(no+t2*16+l15)*32 + l4*8];
    }
    #pragma unroll
    for (int mt=0; mt<4; mt++)
      #pragma unroll
      for (int nt=0; nt<4; nt++)
        acc[mt][nt] = mfma16(a[mt], b[nt], acc[mt][nt]);
    __syncthreads();
  }
  #pragma unroll
  for (int mt=0; mt<4; mt++)
   #pragma unroll
   for (int nt=0; nt<4; nt++)
    #pragma unroll
    for (int i=0; i<4; i++){
      int m = m0 + mo + mt*16 + l4*4 + i;
      int n = n0 + no + nt*16 + l15;
      GI[(size_t)m*G3 + n] = f2bf(acc[mt][nt][i] + bih[n]);
    }
}

// ---------------- compressed scan: R7-proven structure + one-step GI pipeline ----------------
// R8 lesson: flag detection must be ONE lane-parallel load (wave0 polls all 32 flags).
// R10 lesson: GI loads trapped in the staging vmcnt(0) expose cold-miss latency ->
// prefetch a FULL step ahead so latency spans MFMA+reduce+elementwise+poll.
__global__ __launch_bounds__(256,1) void k_scan_c(
    const u16* __restrict__ GI, const u16* __restrict__ Whh,
    const float* __restrict__ bhh,
    const int* __restrict__ nact, const int* __restrict__ meta,
    u16* __restrict__ hcomp, int* __restrict__ flags){
  __shared__ u16 hs[32*1024];          // 64 KiB staged h (swizzled 16B granules)
  __shared__ float red[2*32*RS];       // 25.6 KiB partial sums
  int tid = threadIdx.x;
  int lane = tid & 63, wave = tid >> 6;
  int l15 = lane & 15, l4 = lane >> 4;
  int bi = blockIdx.x & 7, ji = blockIdx.x >> 3;
  int b0 = bi*32, j0 = ji*32;
  int kwi = wave & 1;
  int kw2 = kwi*512;
  int nw  = (wave>>1)*48;

  f4 wff[3][16];                       // resident W_hh slice, asm-pinned
  #pragma unroll
  for (int nt=0; nt<3; nt++){
    int c  = nw + nt*16 + l15;
    int wrow = (c>>5)*H_ + j0 + (c&31);
    #pragma unroll
    for (int ks=0; ks<16; ks++){
      wff[nt][ks] = *(const f4*)&Whh[(size_t)wrow*H_ + kw2 + ks*32 + l4*8];
      asm volatile("" : "+v"(wff[nt][ks]));
    }
  }

  int urow = tid >> 3;
  int c0 = (tid & 7)*4;
  int row_b = b0 + urow;
  float bh[3][4];
  #pragma unroll
  for (int g=0; g<3; g++)
    #pragma unroll
    for (int ci=0; ci<4; ci++)
      bh[g][ci] = bhh[g*H_ + j0 + c0 + ci];
  float hreg[4] = {0.f,0.f,0.f,0.f};
  int na = nact[row_b];
  int Smax = meta[0];

  // prologue: GI for s=0
  u64 gv0 = 0, gv1 = 0, gv2 = 0;
  if (Smax > 0){
    const u16* gib0 = GI + ((size_t)row_b)*G3 + j0 + c0;
    gv0 = *(const u64*)(gib0);
    gv1 = *(const u64*)(gib0 + H_);
    gv2 = *(const u64*)(gib0 + 2*H_);
  }

  for (int s=0; s<Smax; s++){
    // ---- wait: wave 0 polls 32 padded flags in ONE lane-parallel load ----
    if (wave == 0 && s > 0){
      const int* fp = flags + (bi*32 + (lane & 31))*4;
      u32 it = 0;
      for (;;){
        int f = __hip_atomic_load(fp, __ATOMIC_RELAXED, __HIP_MEMORY_SCOPE_AGENT);
        if (__all(f >= s)) break;
        __builtin_amdgcn_s_sleep(1);
        if (++it > 300000u) break;
      }
    }
    __syncthreads();

    // ---- stage h(s-1): 16 x dwordx4 sc0 sc1 plain loads -> swizzled LDS (b128) ----
    if (s == 0){
      uint4 z = {0,0,0,0};
      uint4* hs4 = (uint4*)hs;
      #pragma unroll
      for (int i=0; i<16; i++) hs4[i*256 + tid] = z;
    } else {
      const uint4* hb4 = (const uint4*)(hcomp + (size_t)(s-1)*(B_*H_) + (size_t)b0*H_);
      uint4 r[16];
      #pragma unroll
      for (int i=0; i<16; i++){
        const uint4* p = hb4 + i*256 + tid;
        asm volatile("global_load_dwordx4 %0, %1, off sc0 sc1" : "=v"(r[i]) : "v"(p));
      }
      asm volatile("s_waitcnt vmcnt(0)" ::: "memory");
      __builtin_amdgcn_sched_barrier(0);
      uint4* hs4 = (uint4*)hs;
      #pragma unroll
      for (int i=0; i<16; i++){
        int g = i*256 + tid;            // granule id over 32 rows x 128
        int row = g >> 7, col = g & 127;
        hs4[row*128 + (col ^ (row&7))] = r[i];
      }
    }
    __syncthreads();

    // ---- prefetch GI for s+1: full step of slack before consumption ----
    u64 nv0 = gv0, nv1 = gv1, nv2 = gv2;
    if (s+1 < Smax){
      const u16* gibn = GI + ((size_t)(s+1)*B_ + row_b)*G3 + j0 + c0;
      nv0 = *(const u64*)(gibn);
      nv1 = *(const u64*)(gibn + H_);
      nv2 = *(const u64*)(gibn + 2*H_);
    }

    // ---- MFMA: gh partial (32 rows x 48 cols x K=512 per wave) ----
    f4 acc[2][3] = {};
    #pragma unroll
    for (int ks=0; ks<16; ks++){
      bf16x8 a[2];
      #pragma unroll
      for (int mt=0; mt<2; mt++){
        int row = mt*16 + l15;
        int c16 = (kw2>>3) + ks*4 + l4;
        a[mt] = *(const bf16x8*)&hs[row*1024 + ((c16 ^ (row&7))<<3)];
      }
      #pragma unroll
      for (int mt=0; mt<2; mt++)
        #pragma unroll
        for (int nt=0; nt<3; nt++)
          acc[mt][nt] = mfma16(a[mt], __builtin_bit_cast(bf16x8, wff[nt][ks]), acc[mt][nt]);
    }

    // ---- write partials to LDS ----
    #pragma unroll
    for (int mt=0; mt<2; mt++)
      #pragma unroll
      for (int nt=0; nt<3; nt++)
        #pragma unroll
        for (int i=0; i<4; i++)
          red[(kwi*32 + mt*16 + l4*4 + i)*RS + nw + nt*16 + l15] = acc[mt][nt][i];
    __syncthreads();

    // ---- elementwise GRU update (1 row x 4 cols per thread) ----
    {
      f4 gh[3];
      #pragma unroll
      for (int g=0; g<3; g++){
        f4 s0 = *(const f4*)&red[(0*32+urow)*RS + g*32 + c0];
        f4 s1 = *(const f4*)&red[(1*32+urow)*RS + g*32 + c0];
        gh[g] = s0 + s1;
      }
      bool active = (s < na);
      u16 hb16[4];
      #pragma unroll
      for (int ci=0; ci<4; ci++){
        float ir  = bf2f((u16)(gv0 >> (16*ci)));
        float iz  = bf2f((u16)(gv1 >> (16*ci)));
        float in_ = bf2f((u16)(gv2 >> (16*ci)));
        float r = sigm(ir + gh[0][ci] + bh[0][ci]);
        float z = sigm(iz + gh[1][ci] + bh[1][ci]);
        float n = tanh_f(in_ + r*(gh[2][ci] + bh[2][ci]));
        float hn = (1.f - z)*n + z*hreg[ci];
        hreg[ci] = active ? hn : hreg[ci];
        hb16[ci] = f2bf(hreg[ci]);
      }
      u64 pk = (u64)hb16[0] | ((u64)hb16[1]<<16) | ((u64)hb16[2]<<32) | ((u64)hb16[3]<<48);
      __hip_atomic_store((u64*)&hcomp[(size_t)s*(B_*H_) + (size_t)row_b*H_ + j0 + c0],
                         pk, __ATOMIC_RELAXED, __HIP_MEMORY_SCOPE_AGENT);
    }
    __syncthreads();                   // all threads' h stores drained before flag
    if (tid == 0)
      __hip_atomic_store(&flags[(bi*32 + ji)*4], s+1,
                         __ATOMIC_RELEASE, __HIP_MEMORY_SCOPE_AGENT);
    gv0 = nv0; gv1 = nv1; gv2 = nv2;
  }
}

// ---------------- LayerNorm with hcomp gather: 8 rows (same b) per block ----------------
__global__ __launch_bounds__(256) void k_lng8(const u16* __restrict__ hcomp,
                                              const u16* __restrict__ idx,
                                              const float* __restrict__ g,
                                              const float* __restrict__ b,
                                              float* __restrict__ Y){
  int blk = blockIdx.x;
  int bb = blk >> 6, tt0 = (blk & 63)*8;
  int tid = threadIdx.x;
  float4 gg = ((const float4*)g)[tid];
  float4 bb4 = ((const float4*)b)[tid];
  __shared__ float ss[4], qq[4];
  int wave = tid >> 6;
  #pragma unroll
  for (int rr=0; rr<8; rr++){
    int tt = tt0 + rr;
    int s = (int)idx[bb*T_ + tt];
    float4 v;
    if (s == 0){
      v.x = v.y = v.z = v.w = 0.f;
    } else {
      u64 hv = *(const u64*)(hcomp + (size_t)(s-1)*(B_*H_) + (size_t)bb*H_ + tid*4);
      v.x = bf2f((u16)hv);
      v.y = bf2f((u16)(hv>>16));
      v.z = bf2f((u16)(hv>>32));
      v.w = bf2f((u16)(hv>>48));
    }
    float sm = v.x+v.y+v.z+v.w;
    float q = v.x*v.x+v.y*v.y+v.z*v.z+v.w*v.w;
    #pragma unroll
    for (int off=32; off; off>>=1){ sm += __shfl_down(sm, off); q += __shfl_down(q, off); }
    if ((tid&63)==0){ ss[wave]=sm; qq[wave]=q; }
    __syncthreads();
    sm = ss[0]+ss[1]+ss[2]+ss[3];
    q  = qq[0]+qq[1]+qq[2]+qq[3];
    float mu = sm*(1.f/H_);
    float var = q*(1.f/H_) - mu*mu;
    float rs = rsqrtf(var + 1e-5f);
    float4 o;
    o.x = (v.x-mu)*rs*gg.x + bb4.x;
    o.y = (v.y-mu)*rs*gg.y + bb4.y;
    o.z = (v.z-mu)*rs*gg.z + bb4.z;
    o.w = (v.w-mu)*rs*gg.w + bb4.w;
    ((float4*)(Y + ((size_t)bb*T_ + tt)*H_))[tid] = o;
    __syncthreads();
  }
}

// ================= fallback path (small ws): R9-proven uncompressed =================
__global__ __launch_bounds__(256) void k_phase1(
    const u16* __restrict__ A, const u16* __restrict__ Wi, const u16* __restrict__ Wg,
    const float* __restrict__ bin, const float* __restrict__ bgt,
    const float* __restrict__ cbi, const float* __restrict__ cbg,
    u16* __restrict__ X){
  __shared__ u16 As[128*32];
  __shared__ u16 Bi[64*32];
  __shared__ u16 Bg[64*32];
  int tid = threadIdx.x;
  int lane = tid & 63, wave = tid >> 6;
  int l15 = lane & 15, l4 = lane >> 4;
  int blk = blockIdx.x;
  int chunk = blk >> 7;
  int wi = blk & 127;
  int m0 = (chunk*8 + (wi & 7))*128;
  int n0 = (wi >> 3)*64;
  int mo = (wave&1)*64, no = (wave>>1)*32;
  f4 acc1[4][2] = {}; f4 acc2[4][2] = {};
  for (int k0 = 0; k0 < DIN; k0 += 32){
    int u = tid;
    gload_lds16(A + (m0 + (u>>2))*DIN + k0 + (u&3)*8, As + wave*512);
    u = 256 + tid;
    gload_lds16(A + (m0 + (u>>2))*DIN + k0 + (u&3)*8, As + (4+wave)*512);
    u = tid;
    gload_lds16(Wi + (n0 + (u>>2))*DIN + k0 + (u&3)*8, Bi + wave*512);
    gload_lds16(Wg + (n0 + (u>>2))*DIN + k0 + (u&3)*8, Bg + wave*512);
    __syncthreads();
    bf16x8 a[4], b1[2], b2[2];
    #pragma unroll
    for (int mt=0; mt<4; mt++) a[mt] = *(const bf16x8*)&As[(mo+mt*16+l15)*32 + l4*8];
    #pragma unroll
    for (int nt=0; nt<2; nt++){
      b1[nt] = *(const bf16x8*)&Bi[(no+nt*16+l15)*32 + l4*8];
      b2[nt] = *(const bf16x8*)&Bg[(no+nt*16+l15)*32 + l4*8];
    }
    #pragma unroll
    for (int mt=0; mt<4; mt++)
      #pragma unroll
      for (int nt=0; nt<2; nt++){
        acc1[mt][nt] = mfma16(a[mt], b1[nt], acc1[mt][nt]);
        acc2[mt][nt] = mfma16(a[mt], b2[nt], acc2[mt][nt]);
      }
    __syncthreads();
  }
  #pragma unroll
  for (int mt=0; mt<4; mt++)
   #pragma unroll
   for (int nt=0; nt<2; nt++)
    #pragma unroll
    for (int i=0; i<4; i++){
      int m = m0 + mo + mt*16 + l4*4 + i;
      int n = n0 + no + nt*16 + l15;
      int b = m >> 9;
      float xl = acc1[mt][nt][i] + bin[n] + cbi[b*H_ + n];
      float gl = acc2[mt][nt][i] + bgt[n] + cbg[b*H_ + n];
      X[(size_t)m*H_ + n] = f2bf(tanh_f(xl) * sigm(gl));
    }
}

__global__ __launch_bounds__(256) void k_phase2(
    const u16* __restrict__ X, const u16* __restrict__ W,
    const float* __restrict__ bih, u16* __restrict__ GI){
  __shared__ u16 As[128*32];
  __shared__ u16 Bs[128*32];
  int tid = threadIdx.x;
  int lane = tid & 63, wave = tid >> 6;
  int l15 = lane & 15, l4 = lane >> 4;
  int blk = blockIdx.x;
  int chunk = blk / 96;
  int wi = blk % 96;
  int m0 = (chunk*4 + (wi & 3))*128;
  int n0 = (wi >> 2)*128;
  int mo = (wave&1)*64, no = (wave>>1)*64;
  f4 acc[4][4] = {};
  for (int k0 = 0; k0 < H_; k0 += 32){
    int u = tid;
    gload_lds16(X + (m0 + (u>>2))*H_ + k0 + (u&3)*8, As + wave*512);
    gload_lds16(W + (n0 + (u>>2))*H_ + k0 + (u&3)*8, Bs + wave*512);
    u = 256 + tid;
    gload_lds16(X + (m0 + (u>>2))*H_ + k0 + (u&3)*8, As + (4+wave)*512);
    gload_lds16(W + (n0 + (u>>2))*H_ + k0 + (u&3)*8, Bs + (4+wave)*512);
    __syncthreads();
    bf16x8 a[4], b[4];
    #pragma unroll
    for (int t2=0; t2<4; t2++){
      a[t2] = *(const bf16x8*)&As[(mo+t2*16+l15)*32 + l4*8];
      b[t2] = *(const bf16x8*)&Bs[(no+t2*16+l15)*32 + l4*8];
    }
    #pragma unroll
    for (int mt=0; mt<4; mt++)
      #pragma unroll
      for (int nt=0; nt<4; nt++)
        acc[mt][nt] = mfma16(a[mt], b[nt], acc[mt][nt]);
    __syncthreads();
  }
  #pragma unroll
  for (int mt=0; mt<4; mt++)
   #pragma unroll
   for (int nt=0; nt<4; nt++)
    #pragma unroll
    for (int i=0; i<4; i++){
      int m = m0 + mo + mt*16 + l4*4 + i;
      int n = n0 + no + nt*16 + l15;
      int b = m >> 9, t = m & 511;
      GI[((size_t)t*B_ + b)*G3 + n] = f2bf(acc[mt][nt][i] + bih[n]);
    }
}

__global__ __launch_bounds__(256,1) void k_scan_d(
    const u16* __restrict__ GI, const u16* __restrict__ Whh,
    const float* __restrict__ bhh, const float* __restrict__ mask,
    u16* __restrict__ hbuf, int* __restrict__ flags, float* __restrict__ Y){
  __shared__ u16 hs[32*1024];
  __shared__ float red[2*32*RS];
  int tid = threadIdx.x;
  int lane = tid & 63, wave = tid >> 6;
  int l15 = lane & 15, l4 = lane >> 4;
  int bi = blockIdx.x & 7, ji = blockIdx.x >> 3;
  int b0 = bi*32, j0 = ji*32;
  int kwi = wave & 1;
  int kw2 = kwi*512;
  int nw  = (wave>>1)*48;
  f4 wff[3][16];
  #pragma unroll
  for (int nt=0; nt<3; nt++){
    int c  = nw + nt*16 + l15;
    int wrow = (c>>5)*H_ + j0 + (c&31);
    #pragma unroll
    for (int ks=0; ks<16; ks++){
      wff[nt][ks] = *(const f4*)&Whh[(size_t)wrow*H_ + kw2 + ks*32 + l4*8];
      asm volatile("" : "+v"(wff[nt][ks]));
    }
  }
  int urow = tid >> 3;
  int c0 = (tid & 7)*4;
  float bh[3][4];
  #pragma unroll
  for (int g=0; g<3; g++)
    #pragma unroll
    for (int ci=0; ci<4; ci++)
      bh[g][ci] = bhh[g*H_ + j0 + c0 + ci];
  float hreg[4] = {0.f,0.f,0.f,0.f};
  const float* mrow = mask + (size_t)(b0+urow)*T_;
  u64* hs64 = (u64*)hs;
  for (int t=0; t<T_; t++){
    const u16* gib = GI + ((size_t)t*B_ + (b0+urow))*G3 + j0 + c0;
    u64 gv0 = *(const u64*)(gib);
    u64 gv1 = *(const u64*)(gib + H_);
    u64 gv2 = *(const u64*)(gib + 2*H_);
    float msk = mrow[t];
    if (wave == 0 && t > 0){
      const int* fp = flags + (bi*32 + (lane & 31))*4;
      u32 it = 0;
      for (;;){
        int f = __hip_atomic_load(fp, __ATOMIC_RELAXED, __HIP_MEMORY_SCOPE_AGENT);
        if (__all(f >= t)) break;
        __builtin_amdgcn_s_sleep(1);
        if (++it > 300000u) break;
      }
    }
    __syncthreads();
    {
      const u64* hb = (const u64*)hbuf + (size_t)(t&1)*(B_*H_/4) + (size_t)b0*256;
      #pragma unroll
      for (int ib=0; ib<4; ib++){
        u64 v[8];
        #pragma unroll
        for (int i=0; i<8; i++)
          v[i] = __hip_atomic_load(hb + (ib*8+i)*256 + tid,
                                   __ATOMIC_RELAXED, __HIP_MEMORY_SCOPE_AGENT);
        #pragma unroll
        for (int i=0; i<8; i++){
          int row = ib*8 + i;
          int phys = (((tid>>1) ^ (row&7))<<1) | (tid&1);
          hs64[row*256 + phys] = v[i];
        }
      }
    }
    __syncthreads();
    f4 acc[2][3] = {};
    #pragma unroll
    for (int ks=0; ks<16; ks++){
      bf16x8 a[2];
      #pragma unroll
      for (int mt=0; mt<2; mt++){
        int row = mt*16 + l15;
        int c16 = (kw2>>3) + ks*4 + l4;
        a[mt] = *(const bf16x8*)&hs[row*1024 + ((c16 ^ (row&7))<<3)];
      }
      #pragma unroll
      for (int mt=0; mt<2; mt++)
        #pragma unroll
        for (int nt=0; nt<3; nt++)
          acc[mt][nt] = mfma16(a[mt], __builtin_bit_cast(bf16x8, wff[nt][ks]), acc[mt][nt]);
    }
    #pragma unroll
    for (int mt=0; mt<2; mt++)
      #pragma unroll
      for (int nt=0; nt<3; nt++)
        #pragma unroll
        for (int i=0; i<4; i++)
          red[(kwi*32 + mt*16 + l4*4 + i)*RS + nw + nt*16 + l15] = acc[mt][nt][i];
    __syncthreads();
    {
      f4 gh[3];
      #pragma unroll
      for (int g=0; g<3; g++){
        f4 s0 = *(const f4*)&red[(0*32+urow)*RS + g*32 + c0];
        f4 s1 = *(const f4*)&red[(1*32+urow)*RS + g*32 + c0];
        gh[g] = s0 + s1;
      }
      u16 hb16[4];
      float yv[4];
      #pragma unroll
      for (int ci=0; ci<4; ci++){
        float ir  = bf2f((u16)(gv0 >> (16*ci)));
        float iz  = bf2f((u16)(gv1 >> (16*ci)));
        float in_ = bf2f((u16)(gv2 >> (16*ci)));
        float r = sigm(ir + gh[0][ci] + bh[0][ci]);
        float z = sigm(iz + gh[1][ci] + bh[1][ci]);
        float n = tanh_f(in_ + r*(gh[2][ci] + bh[2][ci]));
        float hn = (1.f - z)*n + z*hreg[ci];
        hreg[ci] = (msk > 0.5f) ? hn : hreg[ci];
        hb16[ci] = f2bf(hreg[ci]);
        yv[ci] = hreg[ci];
      }
      u64 pk = (u64)hb16[0] | ((u64)hb16[1]<<16) | ((u64)hb16[2]<<32) | ((u64)hb16[3]<<48);
      __hip_atomic_store((u64*)&hbuf[(size_t)((t+1)&1)*(B_*H_) + (size_t)(b0+urow)*H_ + j0 + c0],
                         pk, __ATOMIC_RELAXED, __HIP_MEMORY_SCOPE_AGENT);
      float4 yq; yq.x=yv[0]; yq.y=yv[1]; yq.z=yv[2]; yq.w=yv[3];
      *(float4*)&Y[((size_t)(b0+urow)*T_ + t)*H_ + j0 + c0] = yq;
    }
    __syncthreads();
    if (tid == 0)
      __hip_atomic_store(&flags[(bi*32 + ji)*4], t+1,
                         __ATOMIC_RELEASE, __HIP_MEMORY_SCOPE_AGENT);
  }
}

__global__ __launch_bounds__(256) void k_ln(float* __restrict__ Y,
                                            const float* __restrict__ g,
                                            const float* __restrict__ b){
  int row = blockIdx.x, tid = threadIdx.x;
  float4 v = ((const float4*)(Y + (size_t)row*H_))[tid];
  float s = v.x+v.y+v.z+v.w;
  float q = v.x*v.x+v.y*v.y+v.z*v.z+v.w*v.w;
  #pragma unroll
  for (int off=32; off; off>>=1){ s += __shfl_down(s, off); q += __shfl_down(q, off); }
  __shared__ float ss[4], qq[4];
  int wave = tid >> 6;
  if ((tid&63)==0){ ss[wave]=s; qq[wave]=q; }
  __syncthreads();
  s = ss[0]+ss[1]+ss[2]+ss[3];
  q = qq[0]+qq[1]+qq[2]+qq[3];
  float mu = s*(1.f/H_);
  float var = q*(1.f/H_) - mu*mu;
  float rs = rsqrtf(var + 1e-5f);
  float4 gg = ((const float4*)g)[tid];
  float4 bb = ((const float4*)b)[tid];
  float4 o;
  o.x = (v.x-mu)*rs*gg.x + bb.x;
  o.y = (v.y-mu)*rs*gg.y + bb.y;
  o.z = (v.z-mu)*rs*gg.z + bb.z;
  o.w = (v.w-mu)*rs*gg.w + bb.w;
  ((float4*)(Y + (size_t)row*H_))[tid] = o;
}

extern "C" void kernel_launch(void* const* d_in, const int* in_sizes, int n_in,
                              void* d_out, int out_size, void* d_ws, size_t ws_size,
                              hipStream_t stream){
  const float* inputs = (const float*)d_in[0];
  const float* mask   = (const float*)d_in[1];
  const float* cbi    = (const float*)d_in[2];
  const float* cbg    = (const float*)d_in[3];
  const float* W_in   = (const float*)d_in[4];
  const float* b_in   = (const float*)d_in[5];
  const float* W_gate = (const float*)d_in[6];
  const float* b_gate = (const float*)d_in[7];
  const float* W_ih   = (const float*)d_in[8];
  const float* b_ih   = (const float*)d_in[9];
  const float* W_hh   = (const float*)d_in[10];
  const float* b_hh   = (const float*)d_in[11];
  const float* ln_g   = (const float*)d_in[12];
  const float* ln_b   = (const float*)d_in[13];

  char* ws = (char*)d_ws;
  size_t o = 0;
  u16* in_bf  = (u16*)(ws + o); o += (size_t)BT*DIN*2;      // 128 MiB
  u16* wi_bf  = (u16*)(ws + o); o += (size_t)H_*DIN*2;
  u16* wg_bf  = (u16*)(ws + o); o += (size_t)H_*DIN*2;
  u16* wih_bf = (u16*)(ws + o); o += (size_t)G3*H_*2;
  u16* whh_bf = (u16*)(ws + o); o += (size_t)G3*H_*2;
  u16* gi_bf  = (u16*)(ws + o); o += (size_t)T_*B_*G3*2;    // 768 MiB
  u16* actb   = (u16*)(ws + o); o += (size_t)B_*T_*2;       // 256 KiB
  u16* idxb   = (u16*)(ws + o); o += (size_t)B_*T_*2;       // 256 KiB
  int* nactb  = (int*)(ws + o); o += (size_t)B_*4;
  int* meta   = (int*)(ws + o); o += 256;
  int* flags  = (int*)(ws + o); o += (size_t)8*32*4*4;
  u16* hbuf   = (u16*)(ws + o); o += (size_t)2*B_*H_*2;     // 1 MiB (fallback)
  size_t need_direct = o;
  u16* hcomp  = (u16*)(ws + o); o += (size_t)T_*B_*H_*2;    // 256 MiB (compressed)
  size_t need_comp = o;
  if (ws_size < need_direct) return;
  bool comp = (ws_size >= need_comp);

  hipMemsetAsync(flags, 0, (size_t)8*32*4*4, stream);
  if (comp) hipMemsetAsync(meta, 0, 256, stream);
  else      hipMemsetAsync(hbuf, 0, (size_t)2*B_*H_*2, stream);

  k_cast<<<2048,256,0,stream>>>(inputs, in_bf, BT*DIN/8);
  k_cast<<<256, 256,0,stream>>>(W_in,   wi_bf,  H_*DIN/8);
  k_cast<<<256, 256,0,stream>>>(W_gate, wg_bf,  H_*DIN/8);
  k_cast<<<1024,256,0,stream>>>(W_ih,   wih_bf, G3*H_/8);
  k_cast<<<1024,256,0,stream>>>(W_hh,   whh_bf, G3*H_/8);

  u16* X = (u16*)d_out;  // bf16 x_c staged in d_out; dead after phase2

  if (comp){
    k_prep<<<B_,256,0,stream>>>(mask, actb, idxb, nactb, meta);
    k_phase1c<<<16384,256,0,stream>>>(in_bf, wi_bf, wg_bf, actb, meta,
                                      b_in, b_gate, cbi, cbg, X);
    k_phase2c<<<24576,256,0,stream>>>(X, wih_bf, meta, b_ih, gi_bf);
    k_scan_c<<<256,256,0,stream>>>(gi_bf, whh_bf, b_hh, nactb, meta, hcomp, flags);
    k_lng8<<<BT/8,256,0,stream>>>(hcomp, idxb, ln_g, ln_b, (float*)d_out);
  } else {
    k_phase1<<<16384,256,0,stream>>>(in_bf, wi_bf, wg_bf, b_in, b_gate, cbi, cbg, X);
    k_phase2<<<24576,256,0,stream>>>(X, wih_bf, b_ih, gi_bf);
    k_scan_d<<<256,256,0,stream>>>(gi_bf, whh_bf, b_hh, mask, hbuf, flags, (float*)d_out);
    k_ln<<<BT,256,0,stream>>>((float*)d_out, ln_g, ln_b);
  }
}

// Round 12
// 3170.102 us; speedup vs baseline: 1.5192x; 1.0130x over previous
//
#include <hip/hip_runtime.h>
#include <stdint.h>

#define B_ 256
#define T_ 512
#define DIN 512
#define H_ 1024
#define BT (B_*T_)
#define G3 (3*H_)
#define RS 100   // red row stride (floats)

typedef unsigned short u16;
typedef unsigned int u32;
typedef unsigned long long u64;
typedef __attribute__((ext_vector_type(8))) __bf16 bf16x8;
typedef __attribute__((ext_vector_type(4))) float f4;

__device__ __forceinline__ u16 f2bf(float f){
  u32 u = __float_as_uint(f);
  u32 r = u + 0x7fffu + ((u>>16)&1u);
  return (u16)(r>>16);
}
__device__ __forceinline__ float bf2f(u16 u){ return __uint_as_float(((u32)u)<<16); }
__device__ __forceinline__ float sigm(float x){ return 1.f/(1.f+__expf(-x)); }
__device__ __forceinline__ float tanh_f(float x){
  x = fminf(fmaxf(x, -15.f), 15.f);
  float e = __expf(2.f*x);
  return (e-1.f)/(e+1.f);
}
__device__ __forceinline__ void gload_lds16(const u16* g, u16* l){
  __builtin_amdgcn_global_load_lds((const __attribute__((address_space(1))) void*)g,
                                   (__attribute__((address_space(3))) void*)l, 16, 0, 0);
}
__device__ __forceinline__ f4 mfma16(bf16x8 a, bf16x8 b, f4 c){
  return __builtin_amdgcn_mfma_f32_16x16x32_bf16(a, b, c, 0, 0, 0);
}

// ---------------- cast f32 -> bf16, 8 elems/thread ----------------
__global__ __launch_bounds__(256) void k_cast(const float* __restrict__ s,
                                              u16* __restrict__ d, int n8){
  int i = blockIdx.x*256 + threadIdx.x;
  int st = gridDim.x*256;
  for (; i < n8; i += st){
    float4 a = ((const float4*)s)[i*2+0];
    float4 b = ((const float4*)s)[i*2+1];
    uint4 o;
    o.x = (u32)f2bf(a.x) | ((u32)f2bf(a.y)<<16);
    o.y = (u32)f2bf(a.z) | ((u32)f2bf(a.w)<<16);
    o.z = (u32)f2bf(b.x) | ((u32)f2bf(b.y)<<16);
    o.w = (u32)f2bf(b.z) | ((u32)f2bf(b.w)<<16);
    ((uint4*)d)[i] = o;
  }
}

// ---------------- prep: per-row active-step compression of mask ----------------
// meta[0] = global Smax; meta[1+g] = per-group Smax (g = b>>5, 8 groups of 32)
__global__ __launch_bounds__(256) void k_prep(const float* __restrict__ mask,
                                              u16* __restrict__ act, u16* __restrict__ idx,
                                              int* __restrict__ nact, int* __restrict__ meta){
  int b = blockIdx.x, tid = threadIdx.x;
  __shared__ int ps[256];
  const float* mr = mask + (size_t)b*T_;
  int a0 = (mr[2*tid]   > 0.5f) ? 1 : 0;
  int a1 = (mr[2*tid+1] > 0.5f) ? 1 : 0;
  ps[tid] = a0 + a1;
  __syncthreads();
  for (int off=1; off<256; off<<=1){
    int v = ps[tid];
    int u = (tid >= off) ? ps[tid-off] : 0;
    __syncthreads();
    ps[tid] = v + u;
    __syncthreads();
  }
  int excl = tid ? ps[tid-1] : 0;
  int i0 = excl + a0;
  int i1 = i0 + a1;
  idx[b*T_ + 2*tid]   = (u16)i0;
  idx[b*T_ + 2*tid+1] = (u16)i1;
  if (a0) act[b*T_ + i0-1] = (u16)(2*tid);
  if (a1) act[b*T_ + i1-1] = (u16)(2*tid+1);
  int na = ps[255];
  if (tid == 0){
    nact[b] = na;
    atomicMax(&meta[0], na);
    atomicMax(&meta[1 + (b>>5)], na);
  }
  for (int s = na + tid; s < T_; s += 256) act[b*T_ + s] = (u16)(T_-1);
}

// ---------------- phase1c: x_c[s][b] = glu(inputs[b][act[b][s]]) -- M-compressed ----------------
__global__ __launch_bounds__(256) void k_phase1c(
    const u16* __restrict__ A, const u16* __restrict__ Wi, const u16* __restrict__ Wg,
    const u16* __restrict__ act, const int* __restrict__ meta,
    const float* __restrict__ bin, const float* __restrict__ bgt,
    const float* __restrict__ cbi, const float* __restrict__ cbg,
    u16* __restrict__ X){
  __shared__ u16 As[128*32];
  __shared__ u16 Bi[64*32];
  __shared__ u16 Bg[64*32];
  int tid = threadIdx.x;
  int lane = tid & 63, wave = tid >> 6;
  int l15 = lane & 15, l4 = lane >> 4;
  int blk = blockIdx.x;
  int chunk = blk >> 7;
  int wi = blk & 127;
  int m0 = (chunk*8 + (wi & 7))*128;
  int n0 = (wi >> 3)*64;
  if (m0 >= (meta[0] << 8)) return;    // beyond 256*Smax: nothing to compute
  int mo = (wave&1)*64, no = (wave>>1)*32;

  int r0 = m0 + (tid>>2), r1 = r0 + 64;
  int b0r = r0 & 255, s0r = r0 >> 8;
  int b1r = r1 & 255, s1r = r1 >> 8;
  const u16* a0p = A + ((size_t)b0r*T_ + act[b0r*T_ + s0r])*DIN + (tid&3)*8;
  const u16* a1p = A + ((size_t)b1r*T_ + act[b1r*T_ + s1r])*DIN + (tid&3)*8;

  f4 acc1[4][2] = {}; f4 acc2[4][2] = {};
  for (int k0 = 0; k0 < DIN; k0 += 32){
    gload_lds16(a0p + k0, As + wave*512);
    gload_lds16(a1p + k0, As + (4+wave)*512);
    int u = tid;
    gload_lds16(Wi + (n0 + (u>>2))*DIN + k0 + (u&3)*8, Bi + wave*512);
    gload_lds16(Wg + (n0 + (u>>2))*DIN + k0 + (u&3)*8, Bg + wave*512);
    __syncthreads();
    bf16x8 a[4], b1[2], b2[2];
    #pragma unroll
    for (int mt=0; mt<4; mt++) a[mt] = *(const bf16x8*)&As[(mo+mt*16+l15)*32 + l4*8];
    #pragma unroll
    for (int nt=0; nt<2; nt++){
      b1[nt] = *(const bf16x8*)&Bi[(no+nt*16+l15)*32 + l4*8];
      b2[nt] = *(const bf16x8*)&Bg[(no+nt*16+l15)*32 + l4*8];
    }
    #pragma unroll
    for (int mt=0; mt<4; mt++)
      #pragma unroll
      for (int nt=0; nt<2; nt++){
        acc1[mt][nt] = mfma16(a[mt], b1[nt], acc1[mt][nt]);
        acc2[mt][nt] = mfma16(a[mt], b2[nt], acc2[mt][nt]);
      }
    __syncthreads();
  }
  #pragma unroll
  for (int mt=0; mt<4; mt++)
   #pragma unroll
   for (int nt=0; nt<2; nt++)
    #pragma unroll
    for (int i=0; i<4; i++){
      int m = m0 + mo + mt*16 + l4*4 + i;
      int n = n0 + no + nt*16 + l15;
      int b = m & 255;                 // m' = s*256 + b
      float xl = acc1[mt][nt][i] + bin[n] + cbi[b*H_ + n];
      float gl = acc2[mt][nt][i] + bgt[n] + cbg[b*H_ + n];
      X[(size_t)m*H_ + n] = f2bf(tanh_f(xl) * sigm(gl));
    }
}

// ---------------- phase2c: gi_c[m'] = x_c[m'] @ W_ih^T + b_ih (REVERSED chunk order) ----------------
__global__ __launch_bounds__(256) void k_phase2c(
    const u16* __restrict__ X, const u16* __restrict__ W,
    const int* __restrict__ meta, const float* __restrict__ bih,
    u16* __restrict__ GI){
  __shared__ u16 As[128*32];
  __shared__ u16 Bs[128*32];
  int tid = threadIdx.x;
  int lane = tid & 63, wave = tid >> 6;
  int l15 = lane & 15, l4 = lane >> 4;
  int blk = blockIdx.x;
  int chunk = 255 - (blk / 96);        // REVERSED: high m' first, s~0 written last
  int wi = blk % 96;
  int m0 = (chunk*4 + (wi & 3))*128;
  int n0 = (wi >> 2)*128;
  if (m0 >= (meta[0] << 8)) return;
  int mo = (wave&1)*64, no = (wave>>1)*64;
  f4 acc[4][4] = {};
  for (int k0 = 0; k0 < H_; k0 += 32){
    int u = tid;
    gload_lds16(X + (m0 + (u>>2))*H_ + k0 + (u&3)*8, As + wave*512);
    gload_lds16(W + (n0 + (u>>2))*H_ + k0 + (u&3)*8, Bs + wave*512);
    u = 256 + tid;
    gload_lds16(X + (m0 + (u>>2))*H_ + k0 + (u&3)*8, As + (4+wave)*512);
    gload_lds16(W + (n0 + (u>>2))*H_ + k0 + (u&3)*8, Bs + (4+wave)*512);
    __syncthreads();
    bf16x8 a[4], b[4];
    #pragma unroll
    for (int t2=0; t2<4; t2++){
      a[t2] = *(const bf16x8*)&As[(mo+t2*16+l15)*32 + l4*8];
      b[t2] = *(const bf16x8*)&Bs[(no+t2*16+l15)*32 + l4*8];
    }
    #pragma unroll
    for (int mt=0; mt<4; mt++)
      #pragma unroll
      for (int nt=0; nt<4; nt++)
        acc[mt][nt] = mfma16(a[mt], b[nt], acc[mt][nt]);
    __syncthreads();
  }
  #pragma unroll
  for (int mt=0; mt<4; mt++)
   #pragma unroll
   for (int nt=0; nt<4; nt++)
    #pragma unroll
    for (int i=0; i<4; i++){
      int m = m0 + mo + mt*16 + l4*4 + i;
      int n = n0 + no + nt*16 + l15;
      GI[(size_t)m*G3 + n] = f2bf(acc[mt][nt][i] + bih[n]);
    }
}

// ---------------- compressed scan: R11-proven + plain-cached staging + per-group Smax ----------------
// R8 lesson: flag detection = ONE lane-parallel load. R10 lesson: GI prefetched a full step.
// R12: hcomp[s-1] is write-once-read-once FRESH memory -> plain cached loads are coherent
// (producer sc1 write-through + drain before flag; consumer L2 cannot hold a stale line).
// Same-XCD consumer blocks now share one L2 fill (MSHR-merged) instead of 32 LLC round trips.
__global__ __launch_bounds__(256,1) void k_scan_c(
    const u16* __restrict__ GI, const u16* __restrict__ Whh,
    const float* __restrict__ bhh,
    const int* __restrict__ nact, const int* __restrict__ meta,
    u16* __restrict__ hcomp, int* __restrict__ flags){
  __shared__ u16 hs[32*1024];          // 64 KiB staged h (swizzled 16B granules)
  __shared__ float red[2*32*RS];       // 25.6 KiB partial sums
  int tid = threadIdx.x;
  int lane = tid & 63, wave = tid >> 6;
  int l15 = lane & 15, l4 = lane >> 4;
  int bi = blockIdx.x & 7, ji = blockIdx.x >> 3;
  int b0 = bi*32, j0 = ji*32;
  int kwi = wave & 1;
  int kw2 = kwi*512;
  int nw  = (wave>>1)*48;

  f4 wff[3][16];                       // resident W_hh slice, asm-pinned
  #pragma unroll
  for (int nt=0; nt<3; nt++){
    int c  = nw + nt*16 + l15;
    int wrow = (c>>5)*H_ + j0 + (c&31);
    #pragma unroll
    for (int ks=0; ks<16; ks++){
      wff[nt][ks] = *(const f4*)&Whh[(size_t)wrow*H_ + kw2 + ks*32 + l4*8];
      asm volatile("" : "+v"(wff[nt][ks]));
    }
  }

  int urow = tid >> 3;
  int c0 = (tid & 7)*4;
  int row_b = b0 + urow;
  float bh[3][4];
  #pragma unroll
  for (int g=0; g<3; g++)
    #pragma unroll
    for (int ci=0; ci<4; ci++)
      bh[g][ci] = bhh[g*H_ + j0 + c0 + ci];
  float hreg[4] = {0.f,0.f,0.f,0.f};
  int na = nact[row_b];
  int Smax = meta[1 + bi];             // per-group step bound (~3% fewer steps)

  // prologue: GI for s=0
  u64 gv0 = 0, gv1 = 0, gv2 = 0;
  if (Smax > 0){
    const u16* gib0 = GI + ((size_t)row_b)*G3 + j0 + c0;
    gv0 = *(const u64*)(gib0);
    gv1 = *(const u64*)(gib0 + H_);
    gv2 = *(const u64*)(gib0 + 2*H_);
  }

  for (int s=0; s<Smax; s++){
    // ---- wait: wave 0 polls 32 padded flags in ONE lane-parallel load ----
    if (wave == 0 && s > 0){
      const int* fp = flags + (bi*32 + (lane & 31))*4;
      u32 it = 0;
      for (;;){
        int f = __hip_atomic_load(fp, __ATOMIC_RELAXED, __HIP_MEMORY_SCOPE_AGENT);
        if (__all(f >= s)) break;
        __builtin_amdgcn_s_sleep(1);
        if (++it > 300000u) break;
      }
    }
    __syncthreads();

    // ---- stage h(s-1): 16 x dwordx4 PLAIN CACHED loads -> swizzled LDS (b128) ----
    if (s == 0){
      uint4 z = {0,0,0,0};
      uint4* hs4 = (uint4*)hs;
      #pragma unroll
      for (int i=0; i<16; i++) hs4[i*256 + tid] = z;
    } else {
      const uint4* hb4 = (const uint4*)(hcomp + (size_t)(s-1)*(B_*H_) + (size_t)b0*H_);
      uint4 r[16];
      #pragma unroll
      for (int i=0; i<16; i++){
        const uint4* p = hb4 + i*256 + tid;
        asm volatile("global_load_dwordx4 %0, %1, off" : "=v"(r[i]) : "v"(p));
      }
      asm volatile("s_waitcnt vmcnt(0)" ::: "memory");
      __builtin_amdgcn_sched_barrier(0);
      uint4* hs4 = (uint4*)hs;
      #pragma unroll
      for (int i=0; i<16; i++){
        int g = i*256 + tid;            // granule id over 32 rows x 128
        int row = g >> 7, col = g & 127;
        hs4[row*128 + (col ^ (row&7))] = r[i];
      }
    }
    __syncthreads();

    // ---- prefetch GI for s+1: full step of slack before consumption ----
    u64 nv0 = gv0, nv1 = gv1, nv2 = gv2;
    if (s+1 < Smax){
      const u16* gibn = GI + ((size_t)(s+1)*B_ + row_b)*G3 + j0 + c0;
      nv0 = *(const u64*)(gibn);
      nv1 = *(const u64*)(gibn + H_);
      nv2 = *(const u64*)(gibn + 2*H_);
    }

    // ---- MFMA: gh partial (32 rows x 48 cols x K=512 per wave) ----
    f4 acc[2][3] = {};
    #pragma unroll
    for (int ks=0; ks<16; ks++){
      bf16x8 a[2];
      #pragma unroll
      for (int mt=0; mt<2; mt++){
        int row = mt*16 + l15;
        int c16 = (kw2>>3) + ks*4 + l4;
        a[mt] = *(const bf16x8*)&hs[row*1024 + ((c16 ^ (row&7))<<3)];
      }
      #pragma unroll
      for (int mt=0; mt<2; mt++)
        #pragma unroll
        for (int nt=0; nt<3; nt++)
          acc[mt][nt] = mfma16(a[mt], __builtin_bit_cast(bf16x8, wff[nt][ks]), acc[mt][nt]);
    }

    // ---- write partials to LDS ----
    #pragma unroll
    for (int mt=0; mt<2; mt++)
      #pragma unroll
      for (int nt=0; nt<3; nt++)
        #pragma unroll
        for (int i=0; i<4; i++)
          red[(kwi*32 + mt*16 + l4*4 + i)*RS + nw + nt*16 + l15] = acc[mt][nt][i];
    __syncthreads();

    // ---- elementwise GRU update (1 row x 4 cols per thread) ----
    {
      f4 gh[3];
      #pragma unroll
      for (int g=0; g<3; g++){
        f4 s0 = *(const f4*)&red[(0*32+urow)*RS + g*32 + c0];
        f4 s1 = *(const f4*)&red[(1*32+urow)*RS + g*32 + c0];
        gh[g] = s0 + s1;
      }
      bool active = (s < na);
      u16 hb16[4];
      #pragma unroll
      for (int ci=0; ci<4; ci++){
        float ir  = bf2f((u16)(gv0 >> (16*ci)));
        float iz  = bf2f((u16)(gv1 >> (16*ci)));
        float in_ = bf2f((u16)(gv2 >> (16*ci)));
        float r = sigm(ir + gh[0][ci] + bh[0][ci]);
        float z = sigm(iz + gh[1][ci] + bh[1][ci]);
        float n = tanh_f(in_ + r*(gh[2][ci] + bh[2][ci]));
        float hn = (1.f - z)*n + z*hreg[ci];
        hreg[ci] = active ? hn : hreg[ci];
        hb16[ci] = f2bf(hreg[ci]);
      }
      u64 pk = (u64)hb16[0] | ((u64)hb16[1]<<16) | ((u64)hb16[2]<<32) | ((u64)hb16[3]<<48);
      __hip_atomic_store((u64*)&hcomp[(size_t)s*(B_*H_) + (size_t)row_b*H_ + j0 + c0],
                         pk, __ATOMIC_RELAXED, __HIP_MEMORY_SCOPE_AGENT);
    }
    __syncthreads();                   // all threads' h stores drained before flag
    if (tid == 0)
      __hip_atomic_store(&flags[(bi*32 + ji)*4], s+1,
                         __ATOMIC_RELEASE, __HIP_MEMORY_SCOPE_AGENT);
    gv0 = nv0; gv1 = nv1; gv2 = nv2;
  }
}

// ---------------- LayerNorm with hcomp gather: 8 rows (same b) per block ----------------
__global__ __launch_bounds__(256) void k_lng8(const u16* __restrict__ hcomp,
                                              const u16* __restrict__ idx,
                                              const float* __restrict__ g,
                                              const float* __restrict__ b,
                                              float* __restrict__ Y){
  int blk = blockIdx.x;
  int bb = blk >> 6, tt0 = (blk & 63)*8;
  int tid = threadIdx.x;
  float4 gg = ((const float4*)g)[tid];
  float4 bb4 = ((const float4*)b)[tid];
  __shared__ float ss[4], qq[4];
  int wave = tid >> 6;
  #pragma unroll
  for (int rr=0; rr<8; rr++){
    int tt = tt0 + rr;
    int s = (int)idx[bb*T_ + tt];
    float4 v;
    if (s == 0){
      v.x = v.y = v.z = v.w = 0.f;
    } else {
      u64 hv = *(const u64*)(hcomp + (size_t)(s-1)*(B_*H_) + (size_t)bb*H_ + tid*4);
      v.x = bf2f((u16)hv);
      v.y = bf2f((u16)(hv>>16));
      v.z = bf2f((u16)(hv>>32));
      v.w = bf2f((u16)(hv>>48));
    }
    float sm = v.x+v.y+v.z+v.w;
    float q = v.x*v.x+v.y*v.y+v.z*v.z+v.w*v.w;
    #pragma unroll
    for (int off=32; off; off>>=1){ sm += __shfl_down(sm, off); q += __shfl_down(q, off); }
    if ((tid&63)==0){ ss[wave]=sm; qq[wave]=q; }
    __syncthreads();
    sm = ss[0]+ss[1]+ss[2]+ss[3];
    q  = qq[0]+qq[1]+qq[2]+qq[3];
    float mu = sm*(1.f/H_);
    float var = q*(1.f/H_) - mu*mu;
    float rs = rsqrtf(var + 1e-5f);
    float4 o;
    o.x = (v.x-mu)*rs*gg.x + bb4.x;
    o.y = (v.y-mu)*rs*gg.y + bb4.y;
    o.z = (v.z-mu)*rs*gg.z + bb4.z;
    o.w = (v.w-mu)*rs*gg.w + bb4.w;
    ((float4*)(Y + ((size_t)bb*T_ + tt)*H_))[tid] = o;
    __syncthreads();
  }
}

// ================= fallback path (small ws): R9-proven uncompressed =================
__global__ __launch_bounds__(256) void k_phase1(
    const u16* __restrict__ A, const u16* __restrict__ Wi, const u16* __restrict__ Wg,
    const float* __restrict__ bin, const float* __restrict__ bgt,
    const float* __restrict__ cbi, const float* __restrict__ cbg,
    u16* __restrict__ X){
  __shared__ u16 As[128*32];
  __shared__ u16 Bi[64*32];
  __shared__ u16 Bg[64*32];
  int tid = threadIdx.x;
  int lane = tid & 63, wave = tid >> 6;
  int l15 = lane & 15, l4 = lane >> 4;
  int blk = blockIdx.x;
  int chunk = blk >> 7;
  int wi = blk & 127;
  int m0 = (chunk*8 + (wi & 7))*128;
  int n0 = (wi >> 3)*64;
  int mo = (wave&1)*64, no = (wave>>1)*32;
  f4 acc1[4][2] = {}; f4 acc2[4][2] = {};
  for (int k0 = 0; k0 < DIN; k0 += 32){
    int u = tid;
    gload_lds16(A + (m0 + (u>>2))*DIN + k0 + (u&3)*8, As + wave*512);
    u = 256 + tid;
    gload_lds16(A + (m0 + (u>>2))*DIN + k0 + (u&3)*8, As + (4+wave)*512);
    u = tid;
    gload_lds16(Wi + (n0 + (u>>2))*DIN + k0 + (u&3)*8, Bi + wave*512);
    gload_lds16(Wg + (n0 + (u>>2))*DIN + k0 + (u&3)*8, Bg + wave*512);
    __syncthreads();
    bf16x8 a[4], b1[2], b2[2];
    #pragma unroll
    for (int mt=0; mt<4; mt++) a[mt] = *(const bf16x8*)&As[(mo+mt*16+l15)*32 + l4*8];
    #pragma unroll
    for (int nt=0; nt<2; nt++){
      b1[nt] = *(const bf16x8*)&Bi[(no+nt*16+l15)*32 + l4*8];
      b2[nt] = *(const bf16x8*)&Bg[(no+nt*16+l15)*32 + l4*8];
    }
    #pragma unroll
    for (int mt=0; mt<4; mt++)
      #pragma unroll
      for (int nt=0; nt<2; nt++){
        acc1[mt][nt] = mfma16(a[mt], b1[nt], acc1[mt][nt]);
        acc2[mt][nt] = mfma16(a[mt], b2[nt], acc2[mt][nt]);
      }
    __syncthreads();
  }
  #pragma unroll
  for (int mt=0; mt<4; mt++)
   #pragma unroll
   for (int nt=0; nt<2; nt++)
    #pragma unroll
    for (int i=0; i<4; i++){
      int m = m0 + mo + mt*16 + l4*4 + i;
      int n = n0 + no + nt*16 + l15;
      int b = m >> 9;
      float xl = acc1[mt][nt][i] + bin[n] + cbi[b*H_ + n];
      float gl = acc2[mt][nt][i] + bgt[n] + cbg[b*H_ + n];
      X[(size_t)m*H_ + n] = f2bf(tanh_f(xl) * sigm(gl));
    }
}

__global__ __launch_bounds__(256) void k_phase2(
    const u16* __restrict__ X, const u16* __restrict__ W,
    const float* __restrict__ bih, u16* __restrict__ GI){
  __shared__ u16 As[128*32];
  __shared__ u16 Bs[128*32];
  int tid = threadIdx.x;
  int lane = tid & 63, wave = tid >> 6;
  int l15 = lane & 15, l4 = lane >> 4;
  int blk = blockIdx.x;
  int chunk = blk / 96;
  int wi = blk % 96;
  int m0 = (chunk*4 + (wi & 3))*128;
  int n0 = (wi >> 2)*128;
  int mo = (wave&1)*64, no = (wave>>1)*64;
  f4 acc[4][4] = {};
  for (int k0 = 0; k0 < H_; k0 += 32){
    int u = tid;
    gload_lds16(X + (m0 + (u>>2))*H_ + k0 + (u&3)*8, As + wave*512);
    gload_lds16(W + (n0 + (u>>2))*H_ + k0 + (u&3)*8, Bs + wave*512);
    u = 256 + tid;
    gload_lds16(X + (m0 + (u>>2))*H_ + k0 + (u&3)*8, As + (4+wave)*512);
    gload_lds16(W + (n0 + (u>>2))*H_ + k0 + (u&3)*8, Bs + (4+wave)*512);
    __syncthreads();
    bf16x8 a[4], b[4];
    #pragma unroll
    for (int t2=0; t2<4; t2++){
      a[t2] = *(const bf16x8*)&As[(mo+t2*16+l15)*32 + l4*8];
      b[t2] = *(const bf16x8*)&Bs[(no+t2*16+l15)*32 + l4*8];
    }
    #pragma unroll
    for (int mt=0; mt<4; mt++)
      #pragma unroll
      for (int nt=0; nt<4; nt++)
        acc[mt][nt] = mfma16(a[mt], b[nt], acc[mt][nt]);
    __syncthreads();
  }
  #pragma unroll
  for (int mt=0; mt<4; mt++)
   #pragma unroll
   for (int nt=0; nt<4; nt++)
    #pragma unroll
    for (int i=0; i<4; i++){
      int m = m0 + mo + mt*16 + l4*4 + i;
      int n = n0 + no + nt*16 + l15;
      int b = m >> 9, t = m & 511;
      GI[((size_t)t*B_ + b)*G3 + n] = f2bf(acc[mt][nt][i] + bih[n]);
    }
}

__global__ __launch_bounds__(256,1) void k_scan_d(
    const u16* __restrict__ GI, const u16* __restrict__ Whh,
    const float* __restrict__ bhh, const float* __restrict__ mask,
    u16* __restrict__ hbuf, int* __restrict__ flags, float* __restrict__ Y){
  __shared__ u16 hs[32*1024];
  __shared__ float red[2*32*RS];
  int tid = threadIdx.x;
  int lane = tid & 63, wave = tid >> 6;
  int l15 = lane & 15, l4 = lane >> 4;
  int bi = blockIdx.x & 7, ji = blockIdx.x >> 3;
  int b0 = bi*32, j0 = ji*32;
  int kwi = wave & 1;
  int kw2 = kwi*512;
  int nw  = (wave>>1)*48;
  f4 wff[3][16];
  #pragma unroll
  for (int nt=0; nt<3; nt++){
    int c  = nw + nt*16 + l15;
    int wrow = (c>>5)*H_ + j0 + (c&31);
    #pragma unroll
    for (int ks=0; ks<16; ks++){
      wff[nt][ks] = *(const f4*)&Whh[(size_t)wrow*H_ + kw2 + ks*32 + l4*8];
      asm volatile("" : "+v"(wff[nt][ks]));
    }
  }
  int urow = tid >> 3;
  int c0 = (tid & 7)*4;
  float bh[3][4];
  #pragma unroll
  for (int g=0; g<3; g++)
    #pragma unroll
    for (int ci=0; ci<4; ci++)
      bh[g][ci] = bhh[g*H_ + j0 + c0 + ci];
  float hreg[4] = {0.f,0.f,0.f,0.f};
  const float* mrow = mask + (size_t)(b0+urow)*T_;
  u64* hs64 = (u64*)hs;
  for (int t=0; t<T_; t++){
    const u16* gib = GI + ((size_t)t*B_ + (b0+urow))*G3 + j0 + c0;
    u64 gv0 = *(const u64*)(gib);
    u64 gv1 = *(const u64*)(gib + H_);
    u64 gv2 = *(const u64*)(gib + 2*H_);
    float msk = mrow[t];
    if (wave == 0 && t > 0){
      const int* fp = flags + (bi*32 + (lane & 31))*4;
      u32 it = 0;
      for (;;){
        int f = __hip_atomic_load(fp, __ATOMIC_RELAXED, __HIP_MEMORY_SCOPE_AGENT);
        if (__all(f >= t)) break;
        __builtin_amdgcn_s_sleep(1);
        if (++it > 300000u) break;
      }
    }
    __syncthreads();
    {
      const u64* hb = (const u64*)hbuf + (size_t)(t&1)*(B_*H_/4) + (size_t)b0*256;
      #pragma unroll
      for (int ib=0; ib<4; ib++){
        u64 v[8];
        #pragma unroll
        for (int i=0; i<8; i++)
          v[i] = __hip_atomic_load(hb + (ib*8+i)*256 + tid,
                                   __ATOMIC_RELAXED, __HIP_MEMORY_SCOPE_AGENT);
        #pragma unroll
        for (int i=0; i<8; i++){
          int row = ib*8 + i;
          int phys = (((tid>>1) ^ (row&7))<<1) | (tid&1);
          hs64[row*256 + phys] = v[i];
        }
      }
    }
    __syncthreads();
    f4 acc[2][3] = {};
    #pragma unroll
    for (int ks=0; ks<16; ks++){
      bf16x8 a[2];
      #pragma unroll
      for (int mt=0; mt<2; mt++){
        int row = mt*16 + l15;
        int c16 = (kw2>>3) + ks*4 + l4;
        a[mt] = *(const bf16x8*)&hs[row*1024 + ((c16 ^ (row&7))<<3)];
      }
      #pragma unroll
      for (int mt=0; mt<2; mt++)
        #pragma unroll
        for (int nt=0; nt<3; nt++)
          acc[mt][nt] = mfma16(a[mt], __builtin_bit_cast(bf16x8, wff[nt][ks]), acc[mt][nt]);
    }
    #pragma unroll
    for (int mt=0; mt<2; mt++)
      #pragma unroll
      for (int nt=0; nt<3; nt++)
        #pragma unroll
        for (int i=0; i<4; i++)
          red[(kwi*32 + mt*16 + l4*4 + i)*RS + nw + nt*16 + l15] = acc[mt][nt][i];
    __syncthreads();
    {
      f4 gh[3];
      #pragma unroll
      for (int g=0; g<3; g++){
        f4 s0 = *(const f4*)&red[(0*32+urow)*RS + g*32 + c0];
        f4 s1 = *(const f4*)&red[(1*32+urow)*RS + g*32 + c0];
        gh[g] = s0 + s1;
      }
      u16 hb16[4];
      float yv[4];
      #pragma unroll
      for (int ci=0; ci<4; ci++){
        float ir  = bf2f((u16)(gv0 >> (16*ci)));
        float iz  = bf2f((u16)(gv1 >> (16*ci)));
        float in_ = bf2f((u16)(gv2 >> (16*ci)));
        float r = sigm(ir + gh[0][ci] + bh[0][ci]);
        float z = sigm(iz + gh[1][ci] + bh[1][ci]);
        float n = tanh_f(in_ + r*(gh[2][ci] + bh[2][ci]));
        float hn = (1.f - z)*n + z*hreg[ci];
        hreg[ci] = (msk > 0.5f) ? hn : hreg[ci];
        hb16[ci] = f2bf(hreg[ci]);
        yv[ci] = hreg[ci];
      }
      u64 pk = (u64)hb16[0] | ((u64)hb16[1]<<16) | ((u64)hb16[2]<<32) | ((u64)hb16[3]<<48);
      __hip_atomic_store((u64*)&hbuf[(size_t)((t+1)&1)*(B_*H_) + (size_t)(b0+urow)*H_ + j0 + c0],
                         pk, __ATOMIC_RELAXED, __HIP_MEMORY_SCOPE_AGENT);
      float4 yq; yq.x=yv[0]; yq.y=yv[1]; yq.z=yv[2]; yq.w=yv[3];
      *(float4*)&Y[((size_t)(b0+urow)*T_ + t)*H_ + j0 + c0] = yq;
    }
    __syncthreads();
    if (tid == 0)
      __hip_atomic_store(&flags[(bi*32 + ji)*4], t+1,
                         __ATOMIC_RELEASE, __HIP_MEMORY_SCOPE_AGENT);
  }
}

__global__ __launch_bounds__(256) void k_ln(float* __restrict__ Y,
                                            const float* __restrict__ g,
                                            const float* __restrict__ b){
  int row = blockIdx.x, tid = threadIdx.x;
  float4 v = ((const float4*)(Y + (size_t)row*H_))[tid];
  float s = v.x+v.y+v.z+v.w;
  float q = v.x*v.x+v.y*v.y+v.z*v.z+v.w*v.w;
  #pragma unroll
  for (int off=32; off; off>>=1){ s += __shfl_down(s, off); q += __shfl_down(q, off); }
  __shared__ float ss[4], qq[4];
  int wave = tid >> 6;
  if ((tid&63)==0){ ss[wave]=s; qq[wave]=q; }
  __syncthreads();
  s = ss[0]+ss[1]+ss[2]+ss[3];
  q = qq[0]+qq[1]+qq[2]+qq[3];
  float mu = s*(1.f/H_);
  float var = q*(1.f/H_) - mu*mu;
  float rs = rsqrtf(var + 1e-5f);
  float4 gg = ((const float4*)g)[tid];
  float4 bb = ((const float4*)b)[tid];
  float4 o;
  o.x = (v.x-mu)*rs*gg.x + bb.x;
  o.y = (v.y-mu)*rs*gg.y + bb.y;
  o.z = (v.z-mu)*rs*gg.z + bb.z;
  o.w = (v.w-mu)*rs*gg.w + bb.w;
  ((float4*)(Y + (size_t)row*H_))[tid] = o;
}

extern "C" void kernel_launch(void* const* d_in, const int* in_sizes, int n_in,
                              void* d_out, int out_size, void* d_ws, size_t ws_size,
                              hipStream_t stream){
  const float* inputs = (const float*)d_in[0];
  const float* mask   = (const float*)d_in[1];
  const float* cbi    = (const float*)d_in[2];
  const float* cbg    = (const float*)d_in[3];
  const float* W_in   = (const float*)d_in[4];
  const float* b_in   = (const float*)d_in[5];
  const float* W_gate = (const float*)d_in[6];
  const float* b_gate = (const float*)d_in[7];
  const float* W_ih   = (const float*)d_in[8];
  const float* b_ih   = (const float*)d_in[9];
  const float* W_hh   = (const float*)d_in[10];
  const float* b_hh   = (const float*)d_in[11];
  const float* ln_g   = (const float*)d_in[12];
  const float* ln_b   = (const float*)d_in[13];

  char* ws = (char*)d_ws;
  size_t o = 0;
  u16* in_bf  = (u16*)(ws + o); o += (size_t)BT*DIN*2;      // 128 MiB
  u16* wi_bf  = (u16*)(ws + o); o += (size_t)H_*DIN*2;
  u16* wg_bf  = (u16*)(ws + o); o += (size_t)H_*DIN*2;
  u16* wih_bf = (u16*)(ws + o); o += (size_t)G3*H_*2;
  u16* whh_bf = (u16*)(ws + o); o += (size_t)G3*H_*2;
  u16* gi_bf  = (u16*)(ws + o); o += (size_t)T_*B_*G3*2;    // 768 MiB
  u16* actb   = (u16*)(ws + o); o += (size_t)B_*T_*2;       // 256 KiB
  u16* idxb   = (u16*)(ws + o); o += (size_t)B_*T_*2;       // 256 KiB
  int* nactb  = (int*)(ws + o); o += (size_t)B_*4;
  int* meta   = (int*)(ws + o); o += 256;
  int* flags  = (int*)(ws + o); o += (size_t)8*32*4*4;
  u16* hbuf   = (u16*)(ws + o); o += (size_t)2*B_*H_*2;     // 1 MiB (fallback)
  size_t need_direct = o;
  u16* hcomp  = (u16*)(ws + o); o += (size_t)T_*B_*H_*2;    // 256 MiB (compressed)
  size_t need_comp = o;
  if (ws_size < need_direct) return;
  bool comp = (ws_size >= need_comp);

  hipMemsetAsync(flags, 0, (size_t)8*32*4*4, stream);
  if (comp) hipMemsetAsync(meta, 0, 256, stream);
  else      hipMemsetAsync(hbuf, 0, (size_t)2*B_*H_*2, stream);

  k_cast<<<2048,256,0,stream>>>(inputs, in_bf, BT*DIN/8);
  k_cast<<<256, 256,0,stream>>>(W_in,   wi_bf,  H_*DIN/8);
  k_cast<<<256, 256,0,stream>>>(W_gate, wg_bf,  H_*DIN/8);
  k_cast<<<1024,256,0,stream>>>(W_ih,   wih_bf, G3*H_/8);
  k_cast<<<1024,256,0,stream>>>(W_hh,   whh_bf, G3*H_/8);

  u16* X = (u16*)d_out;  // bf16 x_c staged in d_out; dead after phase2

  if (comp){
    k_prep<<<B_,256,0,stream>>>(mask, actb, idxb, nactb, meta);
    k_phase1c<<<16384,256,0,stream>>>(in_bf, wi_bf, wg_bf, actb, meta,
                                      b_in, b_gate, cbi, cbg, X);
    k_phase2c<<<24576,256,0,stream>>>(X, wih_bf, meta, b_ih, gi_bf);
    k_scan_c<<<256,256,0,stream>>>(gi_bf, whh_bf, b_hh, nactb, meta, hcomp, flags);
    k_lng8<<<BT/8,256,0,stream>>>(hcomp, idxb, ln_g, ln_b, (float*)d_out);
  } else {
    k_phase1<<<16384,256,0,stream>>>(in_bf, wi_bf, wg_bf, b_in, b_gate, cbi, cbg, X);
    k_phase2<<<24576,256,0,stream>>>(X, wih_bf, b_ih, gi_bf);
    k_scan_d<<<256,256,0,stream>>>(gi_bf, whh_bf, b_hh, mask, hbuf, flags, (float*)d_out);
    k_ln<<<BT,256,0,stream>>>((float*)d_out, ln_g, ln_b);
  }
}